// Round 7
// baseline (235.650 us; speedup 1.0000x reference)
//
#include <hip/hip_runtime.h>
#include <math.h>

#define EPS   1e-5f
#define NQ    12
#define DEPTH 3
#define BATCH 512
#define DIM   4096   // 2^NQ

__device__ inline float2 cmul(float2 a, float2 b) {
    return make_float2(a.x*b.x - a.y*b.y, a.x*b.y + a.y*b.x);
}
__device__ inline float2 cmac2(float2 ua, float2 s, float2 ub, float2 p) {
    return make_float2(ua.x*s.x - ua.y*s.y + ub.x*p.x - ub.y*p.y,
                       ua.x*s.y + ua.y*s.x + ub.x*p.y + ub.y*p.x);
}

// ===========================================================================
// qsim 8-amp/thread building blocks. 512 threads/sample, k = 3 amp bits.
// Window layout: amp = (t>>HB)<<(HB+3) | k<<HB | (t & ((1<<HB)-1))
// HB=9: k = qubits 0,1,2 ... HB=0: k = qubits 9,10,11 (k bit2=q_s, b1=q_{s+1}, b0=q_{s+2})
// ===========================================================================
__device__ inline int swz(int a) { return a ^ ((a >> 4) & 15); }

template<int HB> __device__ inline int ampl8(int t, int k) {
    return ((t >> HB) << (HB+3)) | (k << HB) | (t & ((1<<HB)-1));
}

template<int FHB, int THB>
__device__ inline void remap8(float2* amp, float2* lds2, int t) {
    #pragma unroll
    for (int k = 0; k < 8; ++k) lds2[swz(ampl8<FHB>(t, k))] = amp[k];
    __syncthreads();
    #pragma unroll
    for (int k = 0; k < 8; ++k) amp[k] = lds2[swz(ampl8<THB>(t, k))];
    __syncthreads();
}

template<int BP>
__device__ inline void one_q8(float2* amp, float2 u00, float2 u01, float2 u10, float2 u11) {
    #pragma unroll
    for (int g = 0; g < 4; ++g) {
        const int j0 = ((g >> BP) << (BP+1)) | (g & ((1<<BP)-1));
        const int j1 = j0 | (1 << BP);
        float2 a0 = amp[j0], a1 = amp[j1];
        amp[j0] = cmac2(u00, a0, u01, a1);
        amp[j1] = cmac2(u10, a0, u11, a1);
    }
}

template<int CB, int TB>
__device__ inline void cry8(float2* amp, float co, float si) {
    #pragma unroll
    for (int m = 0; m < 8; ++m) {
        if (((m >> CB) & 1) && !((m >> TB) & 1)) {
            const int j1 = m | (1 << TB);
            float2 a0 = amp[m], a1 = amp[j1];
            amp[m]  = make_float2(co*a0.x - si*a1.x, co*a0.y - si*a1.y);
            amp[j1] = make_float2(si*a0.x + co*a1.x, si*a0.y + co*a1.y);
        }
    }
}

__device__ void consts_body(int t,
        const float* rot0, const float* ent0, const float* rot1, const float* ent1,
        float2* Uc, float2* Cc) {
    if (t < 72) {
        int layer = t / 36, rem = t % 36, d = rem / 12, q = rem % 12;
        const float* rot = layer ? rot1 : rot0;
        float hx = 0.5f * rot[(d*NQ + q)*3 + 0];
        float hy = 0.5f * rot[(d*NQ + q)*3 + 1];
        float hz = 0.5f * rot[(d*NQ + q)*3 + 2];
        float cx = cosf(hx), sx = sinf(hx);
        float cy = cosf(hy), sy = sinf(hy);
        float2 m00 = make_float2( cy*cx,  sy*sx);
        float2 m01 = make_float2(-sy*cx, -cy*sx);
        float2 m10 = make_float2( sy*cx, -cy*sx);
        float2 m11 = make_float2( cy*cx, -sy*sx);
        float2 ez  = make_float2(cosf(hz), -sinf(hz));
        float2 ezc = make_float2(ez.x, -ez.y);
        float2* U = Uc + t*4;
        U[0] = cmul(ez,  m00);
        U[1] = cmul(ez,  m01);
        U[2] = cmul(ezc, m10);
        U[3] = cmul(ezc, m11);
    } else if (t < 72 + 66) {
        int idx = t - 72, layer = idx / 33, rem = idx % 33;
        const float* ent = layer ? ent1 : ent0;
        float th = 0.5f * ent[rem];
        Cc[idx] = make_float2(cosf(th), sinf(th));
    }
}

// ===========================================================================
// K1: encode layer-0 (blocks 0..127, 4 rows each) + consts (block 128)
// ===========================================================================
__global__ __launch_bounds__(256) void encode0_consts_kernel(
        const float* __restrict__ X, const float* __restrict__ We,
        const float* __restrict__ be, float* __restrict__ Yraw,
        const float* __restrict__ rot0, const float* __restrict__ ent0,
        const float* __restrict__ rot1, const float* __restrict__ ent1,
        float2* __restrict__ Uc, float2* __restrict__ Cc) {
    int tid = threadIdx.x;
    if (blockIdx.x == 128) {
        consts_body(tid, rot0, ent0, rot1, ent1, Uc, Cc);
        return;
    }
    __shared__ float w[NQ][512];
    {
        const float4* src = (const float4*)We;
        float4* dst = (float4*)&w[0][0];
        #pragma unroll
        for (int i = tid; i < NQ*128; i += 256) dst[i] = src[i];
    }
    __syncthreads();
    int wave = tid >> 6, lane = tid & 63;
    int b = blockIdx.x * 4 + wave;
    const float4* xr = (const float4*)(X + (size_t)b * 512);
    float acc[NQ] = {};
    #pragma unroll
    for (int j = 0; j < 2; ++j) {
        float4 xv = xr[lane + 64*j];
        #pragma unroll
        for (int q = 0; q < NQ; ++q) {
            float4 wv = ((const float4*)&w[q][0])[lane + 64*j];
            acc[q] += xv.x*wv.x + xv.y*wv.y + xv.z*wv.z + xv.w*wv.w;
        }
    }
    #pragma unroll
    for (int q = 0; q < NQ; ++q) {
        float v = acc[q];
        #pragma unroll
        for (int off = 32; off; off >>= 1) v += __shfl_xor(v, off);
        if (lane == q) Yraw[b*NQ + q] = v + be[q];
    }
}

// ===========================================================================
// K2/K5: qsim, 512 thr/sample, 8 amps/thread, fused batch-BN + tanh + norm.
// Gate schedule uses 6 overlapping 3-qubit windows; disjoint-qubit gates
// commute so interleaving is exact (every CRY(i,i+1) follows U_i, U_{i+1};
// CRY chain order preserved).
// ===========================================================================
__global__ __launch_bounds__(512, 4) void qsim8_kernel(
        const float* __restrict__ Yraw, const float* __restrict__ gi,
        const float* __restrict__ bi, const float2* __restrict__ UcAll,
        const float2* __restrict__ CcAll, int layer,
        float* __restrict__ mout, float* __restrict__ zeroY) {
    int blk = blockIdx.x, t = threadIdx.x;
    const float2* Uc = UcAll + layer * DEPTH * NQ * 4;
    const float2* Cc = CcAll + layer * DEPTH * (NQ - 1);
    __shared__ float2 lds2[DIM];
    __shared__ float sred[192];
    if (zeroY && t < NQ) zeroY[blk*NQ + t] = 0.f;

    // batch stats: thread t owns row t (3 float4 = 12 floats)
    float sum[NQ], sq[NQ];
    {
        const float4* Y4 = (const float4*)Yraw;
        float4 va = Y4[t*3+0], vb = Y4[t*3+1], vc = Y4[t*3+2];
        float r[12] = {va.x,va.y,va.z,va.w, vb.x,vb.y,vb.z,vb.w, vc.x,vc.y,vc.z,vc.w};
        #pragma unroll
        for (int q = 0; q < NQ; ++q) { sum[q] = r[q]; sq[q] = r[q]*r[q]; }
    }
    int lane = t & 63, wave = t >> 6;
    #pragma unroll
    for (int q = 0; q < NQ; ++q) {
        #pragma unroll
        for (int off = 32; off; off >>= 1) {
            sum[q] += __shfl_xor(sum[q], off);
            sq[q]  += __shfl_xor(sq[q],  off);
        }
    }
    if (lane == 0) {
        #pragma unroll
        for (int q = 0; q < NQ; ++q) {
            sred[wave*24 + q]      = sum[q];
            sred[wave*24 + 12 + q] = sq[q];
        }
    }
    __syncthreads();
    float a[NQ]; float n2 = 0.f;
    const float* yr = Yraw + blk*NQ;
    #pragma unroll
    for (int q = 0; q < NQ; ++q) {
        float s = 0.f, s2 = 0.f;
        #pragma unroll
        for (int w8 = 0; w8 < 8; ++w8) { s += sred[w8*24 + q]; s2 += sred[w8*24 + 12 + q]; }
        float mu  = s  * (1.f/512.f);
        float var = s2 * (1.f/512.f) - mu*mu;
        float val = (yr[q] - mu) * rsqrtf(var + EPS) * gi[q] + bi[q];
        a[q] = tanhf(val);
        n2 += a[q]*a[q];
    }
    float scn = (n2 > 0.f) ? rsqrtf(n2) : 1.f;
    #pragma unroll
    for (int q = 0; q < NQ; ++q) a[q] *= scn;

    // init vectors (encode RY fused with depth-0 U)
    float2 v0[NQ], v1[NQ];
    #pragma unroll
    for (int q = 0; q < NQ; ++q) {
        float sv = fminf(fabsf(a[q]), 1.f);
        float c  = sqrtf(fmaxf(1.f - sv*sv, 0.f));
        float ss = (a[q] < 0.f) ? -sv : sv;
        const float2* U = Uc + q*4;
        v0[q] = make_float2(U[0].x*c + U[1].x*ss, U[0].y*c + U[1].y*ss);
        v1[q] = make_float2(U[2].x*c + U[3].x*ss, U[2].y*c + U[3].y*ss);
    }
    // product state in window A (HB=9): t bit j = qubit 11-j (j=0..8);
    // k bit m = qubit 2-m
    float2 common = make_float2(1.f, 0.f);
    #pragma unroll
    for (int j = 0; j < 9; ++j)
        common = cmul(common, ((t >> j) & 1) ? v1[11-j] : v0[11-j]);
    float2 amp[8];
    amp[0] = common;
    #pragma unroll
    for (int m = 0; m < 3; ++m) {
        const int q = 2 - m;
        #pragma unroll
        for (int k = 0; k < (1<<m); ++k) {
            amp[k | (1<<m)] = cmul(amp[k], v1[q]);
            amp[k]          = cmul(amp[k], v0[q]);
        }
    }

    for (int d = 0; d < DEPTH; ++d) {
        const float2* Ud = Uc + d*NQ*4;
        const float2* Cd = Cc + d*(NQ-1);
        // window A: k = q{0,1,2}
        if (d > 0) {
            one_q8<2>(amp, Ud[0],  Ud[1],  Ud[2],  Ud[3]);    // U0
            one_q8<1>(amp, Ud[4],  Ud[5],  Ud[6],  Ud[7]);    // U1
            one_q8<0>(amp, Ud[8],  Ud[9],  Ud[10], Ud[11]);   // U2
        }
        cry8<2,1>(amp, Cd[0].x, Cd[0].y);   // CRY 0-1
        cry8<1,0>(amp, Cd[1].x, Cd[1].y);   // CRY 1-2
        remap8<9,7>(amp, lds2, t);
        // window B: k = q{2,3,4}
        if (d > 0) {
            one_q8<1>(amp, Ud[12], Ud[13], Ud[14], Ud[15]);   // U3
            one_q8<0>(amp, Ud[16], Ud[17], Ud[18], Ud[19]);   // U4
        }
        cry8<2,1>(amp, Cd[2].x, Cd[2].y);   // CRY 2-3
        cry8<1,0>(amp, Cd[3].x, Cd[3].y);   // CRY 3-4
        remap8<7,5>(amp, lds2, t);
        // window C: k = q{4,5,6}
        if (d > 0) {
            one_q8<1>(amp, Ud[20], Ud[21], Ud[22], Ud[23]);   // U5
            one_q8<0>(amp, Ud[24], Ud[25], Ud[26], Ud[27]);   // U6
        }
        cry8<2,1>(amp, Cd[4].x, Cd[4].y);   // CRY 4-5
        cry8<1,0>(amp, Cd[5].x, Cd[5].y);   // CRY 5-6
        remap8<5,3>(amp, lds2, t);
        // window D: k = q{6,7,8}
        if (d > 0) {
            one_q8<1>(amp, Ud[28], Ud[29], Ud[30], Ud[31]);   // U7
            one_q8<0>(amp, Ud[32], Ud[33], Ud[34], Ud[35]);   // U8
        }
        cry8<2,1>(amp, Cd[6].x, Cd[6].y);   // CRY 6-7
        cry8<1,0>(amp, Cd[7].x, Cd[7].y);   // CRY 7-8
        remap8<3,1>(amp, lds2, t);
        // window E: k = q{8,9,10}
        if (d > 0) {
            one_q8<1>(amp, Ud[36], Ud[37], Ud[38], Ud[39]);   // U9
            one_q8<0>(amp, Ud[40], Ud[41], Ud[42], Ud[43]);   // U10
        }
        cry8<2,1>(amp, Cd[8].x, Cd[8].y);   // CRY 8-9
        cry8<1,0>(amp, Cd[9].x, Cd[9].y);   // CRY 9-10
        remap8<1,0>(amp, lds2, t);
        // window F: k = q{9,10,11}
        if (d > 0) {
            one_q8<0>(amp, Ud[44], Ud[45], Ud[46], Ud[47]);   // U11
        }
        cry8<1,0>(amp, Cd[10].x, Cd[10].y); // CRY 10-11
        if (d < DEPTH-1) remap8<0,9>(amp, lds2, t);
    }

    // measurement in window F: amp = t<<3 | k; k b2=q9,b1=q10,b0=q11;
    // t bit j = qubit 8-j
    float msum = 0.f, p9 = 0.f, p10 = 0.f, p11 = 0.f;
    #pragma unroll
    for (int k = 0; k < 8; ++k) {
        float m = amp[k].x*amp[k].x + amp[k].y*amp[k].y;
        msum += m;
        if (k & 4) p9  += m;
        if (k & 2) p10 += m;
        if (k & 1) p11 += m;
    }
    #pragma unroll
    for (int q = 0; q < NQ; ++q) {
        float v;
        if (q < 9)        v = ((t >> (8-q)) & 1) ? msum : 0.f;
        else if (q == 9)  v = p9;
        else if (q == 10) v = p10;
        else              v = p11;
        #pragma unroll
        for (int off = 32; off; off >>= 1) v += __shfl_xor(v, off);
        if (lane == 0) sred[q*8 + wave] = v;
    }
    __syncthreads();
    if (t < NQ) {
        float r = 0.f;
        #pragma unroll
        for (int w8 = 0; w8 < 8; ++w8) r += sred[t*8 + w8];
        mout[blk*NQ + t] = r;
    }
}

// ===========================================================================
// K3/K6: decode (block = hidden unit h), BN over batch, write transposed.
// ===========================================================================
__global__ __launch_bounds__(512) void decode_kernel(
        const float* __restrict__ m, const float* __restrict__ Wd,
        const float* __restrict__ bd, const float* __restrict__ go,
        const float* __restrict__ bo, float* __restrict__ outT) {
    int h = blockIdx.x, b = threadIdx.x;
    __shared__ float sm[BATCH * 13];
    __shared__ float2 red[8];
    const float4* m4 = (const float4*)m;
    for (int f4 = b; f4 < 1536; f4 += 512) {
        float4 v = m4[f4];
        int base = f4*4; int row = base/12; int q = base - row*12;
        float* dst = sm + row*13 + q;
        dst[0]=v.x; dst[1]=v.y; dst[2]=v.z; dst[3]=v.w;
    }
    __syncthreads();
    float z = bd[h];
    #pragma unroll
    for (int q = 0; q < NQ; ++q) z += sm[b*13 + q] * Wd[h*NQ + q];
    float2 v = make_float2(z, z*z);
    int lane = b & 63, wave = b >> 6;
    for (int off = 32; off; off >>= 1) { v.x += __shfl_down(v.x, off); v.y += __shfl_down(v.y, off); }
    if (lane == 0) red[wave] = v;
    __syncthreads();
    float s = 0.f, s2 = 0.f;
    #pragma unroll
    for (int wv = 0; wv < 8; ++wv) { s += red[wv].x; s2 += red[wv].y; }
    float mu  = s  * (1.f/512.f);
    float var = s2 * (1.f/512.f) - mu*mu;
    outT[(size_t)h*BATCH + b] = (z - mu) * rsqrtf(var + EPS) * go[h] + bo[h];
}

// ===========================================================================
// K4: encode layer-1 straight from k-major h1T (128 blocks, atomic partials)
// ===========================================================================
__global__ __launch_bounds__(256) void encode1_kernel(
        const float* __restrict__ h1T, const float* __restrict__ We,
        const float* __restrict__ be, float* __restrict__ Yraw1) {
    __shared__ float w[NQ][512];
    __shared__ float red[4*64*NQ];
    int tid = threadIdx.x, blk = blockIdx.x;
    {
        const float4* src = (const float4*)We;
        float4* dst = (float4*)&w[0][0];
        #pragma unroll
        for (int i = tid; i < NQ*128; i += 256) dst[i] = src[i];
    }
    __syncthreads();
    int kc = blk >> 3, bc = blk & 7;     // kc in [0,16): 32 h each
    int bl = tid & 63, hg = tid >> 6;
    int b = bc*64 + bl;
    float acc[NQ] = {};
    #pragma unroll
    for (int i = 0; i < 8; ++i) {
        int h = kc*32 + hg*8 + i;
        float xv = h1T[(size_t)h*512 + b];
        #pragma unroll
        for (int q = 0; q < NQ; ++q) acc[q] += xv * w[q][h];
    }
    #pragma unroll
    for (int q = 0; q < NQ; ++q) red[(hg*64 + bl)*NQ + q] = acc[q];
    __syncthreads();
    for (int i = tid; i < 64*NQ; i += 256) {
        int bl2 = i / NQ, q = i - bl2*NQ;
        float v = red[bl2*NQ+q] + red[(64+bl2)*NQ+q] + red[(128+bl2)*NQ+q] + red[(192+bl2)*NQ+q];
        if (kc == 0) v += be[q];
        atomicAdd(&Yraw1[(size_t)(bc*64 + bl2)*NQ + q], v);
    }
}

// ===========================================================================
// K7: GEMM1 split-K4: BM=64 BN=64 BK=32, grid (8,16,4), dbuf LDS.
// ===========================================================================
__global__ __launch_bounds__(256) void gemm1_kernel(
        const float* __restrict__ AT, const float* __restrict__ W,
        float* __restrict__ Cpart) {     // [4][512][1024]
    __shared__ float As[2][32][64];
    __shared__ float Bs[2][32][68];
    const int b0 = blockIdx.x * 64, j0 = blockIdx.y * 64;
    const int kbase = blockIdx.z * 128;
    float* C = Cpart + (size_t)blockIdx.z * 512 * 1024;
    const int tid = threadIdx.x;
    const int tr = tid >> 4, tc = tid & 15;
    const int a_kk = tid >> 4, a_f4 = tid & 15;
    const int b_jj = tid >> 3, b_k4 = (tid & 7) * 4;
    float4 ra0, ra1, rb0, rb1;
    float acc[4][4] = {};
    {
        const int k0 = kbase;
        ra0 = *(const float4*)(AT + (size_t)(k0 + a_kk)*512 + b0 + a_f4*4);
        ra1 = *(const float4*)(AT + (size_t)(k0 + a_kk + 16)*512 + b0 + a_f4*4);
        rb0 = *(const float4*)(W + (size_t)(j0 + b_jj)*512 + k0 + b_k4);
        rb1 = *(const float4*)(W + (size_t)(j0 + b_jj + 32)*512 + k0 + b_k4);
        *(float4*)&As[0][a_kk][a_f4*4] = ra0;
        *(float4*)&As[0][a_kk+16][a_f4*4] = ra1;
        Bs[0][b_k4+0][b_jj] = rb0.x; Bs[0][b_k4+1][b_jj] = rb0.y;
        Bs[0][b_k4+2][b_jj] = rb0.z; Bs[0][b_k4+3][b_jj] = rb0.w;
        Bs[0][b_k4+0][b_jj+32] = rb1.x; Bs[0][b_k4+1][b_jj+32] = rb1.y;
        Bs[0][b_k4+2][b_jj+32] = rb1.z; Bs[0][b_k4+3][b_jj+32] = rb1.w;
    }
    __syncthreads();
    for (int s = 0; s < 4; ++s) {
        if (s < 3) {
            const int k0 = kbase + (s+1)*32;
            ra0 = *(const float4*)(AT + (size_t)(k0 + a_kk)*512 + b0 + a_f4*4);
            ra1 = *(const float4*)(AT + (size_t)(k0 + a_kk + 16)*512 + b0 + a_f4*4);
            rb0 = *(const float4*)(W + (size_t)(j0 + b_jj)*512 + k0 + b_k4);
            rb1 = *(const float4*)(W + (size_t)(j0 + b_jj + 32)*512 + k0 + b_k4);
        }
        const int bf = s & 1;
        #pragma unroll
        for (int kk = 0; kk < 32; ++kk) {
            float4 a  = *(const float4*)&As[bf][kk][tr*4];
            float4 bv = *(const float4*)&Bs[bf][kk][tc*4];
            acc[0][0] += a.x*bv.x; acc[0][1] += a.x*bv.y; acc[0][2] += a.x*bv.z; acc[0][3] += a.x*bv.w;
            acc[1][0] += a.y*bv.x; acc[1][1] += a.y*bv.y; acc[1][2] += a.y*bv.z; acc[1][3] += a.y*bv.w;
            acc[2][0] += a.z*bv.x; acc[2][1] += a.z*bv.y; acc[2][2] += a.z*bv.z; acc[2][3] += a.z*bv.w;
            acc[3][0] += a.w*bv.x; acc[3][1] += a.w*bv.y; acc[3][2] += a.w*bv.z; acc[3][3] += a.w*bv.w;
        }
        if (s < 3) {
            const int nb = bf ^ 1;
            *(float4*)&As[nb][a_kk][a_f4*4] = ra0;
            *(float4*)&As[nb][a_kk+16][a_f4*4] = ra1;
            Bs[nb][b_k4+0][b_jj] = rb0.x; Bs[nb][b_k4+1][b_jj] = rb0.y;
            Bs[nb][b_k4+2][b_jj] = rb0.z; Bs[nb][b_k4+3][b_jj] = rb0.w;
            Bs[nb][b_k4+0][b_jj+32] = rb1.x; Bs[nb][b_k4+1][b_jj+32] = rb1.y;
            Bs[nb][b_k4+2][b_jj+32] = rb1.z; Bs[nb][b_k4+3][b_jj+32] = rb1.w;
        }
        __syncthreads();
    }
    #pragma unroll
    for (int r = 0; r < 4; ++r) {
        float4 o = make_float4(acc[r][0], acc[r][1], acc[r][2], acc[r][3]);
        *(float4*)(C + (size_t)(b0 + tr*4 + r)*1024 + j0 + tc*4) = o;
    }
}

// K8: LN+ReLU over rows of 1024; input = sum of 4 K-partials + bias.
__global__ __launch_bounds__(256) void ln_relu_kernel(
        const float* __restrict__ P, const float* __restrict__ bias,
        const float* __restrict__ g, const float* __restrict__ be,
        float* __restrict__ Y) {
    int b = blockIdx.x, tid = threadIdx.x;
    __shared__ float2 red[4];
    float v[4];
    #pragma unroll
    for (int j = 0; j < 4; ++j) {
        int col = tid + j*256;
        float t = bias[col];
        #pragma unroll
        for (int z = 0; z < 4; ++z) t += P[(size_t)z*524288 + (size_t)b*1024 + col];
        v[j] = t;
    }
    float2 r = make_float2(v[0]+v[1]+v[2]+v[3],
                           v[0]*v[0]+v[1]*v[1]+v[2]*v[2]+v[3]*v[3]);
    int lane = tid & 63, wave = tid >> 6;
    for (int off = 32; off; off >>= 1) { r.x += __shfl_down(r.x, off); r.y += __shfl_down(r.y, off); }
    if (lane == 0) red[wave] = r;
    __syncthreads();
    float s = red[0].x + red[1].x + red[2].x + red[3].x;
    float s2 = red[0].y + red[1].y + red[2].y + red[3].y;
    float mu  = s  * (1.f/1024.f);
    float var = s2 * (1.f/1024.f) - mu*mu;
    float inv = rsqrtf(var + EPS);
    float* yr = Y + (size_t)b * 1024;
    #pragma unroll
    for (int j = 0; j < 4; ++j) {
        int col = tid + j*256;
        yr[col] = fmaxf((v[j]-mu)*inv*g[col] + be[col], 0.f);
    }
}

// K9: GEMM2 split-K8: BM=32 BN=64 BK=32, grid (16,4,8), dbuf LDS.
__global__ __launch_bounds__(256) void gemm2_kernel(
        const float* __restrict__ Amat, const float* __restrict__ W,
        float* __restrict__ Cpart) {     // [8][512][256]
    __shared__ __align__(16) char smem[27000];
    float (*As)[32][36] = (float(*)[32][36])smem;
    float (*Bs)[32][68] = (float(*)[32][68])(smem + 9216);
    const int b0 = blockIdx.x * 32, j0 = blockIdx.y * 64;
    const int kbase = blockIdx.z * 128;
    float* C = Cpart + (size_t)blockIdx.z * 512 * 256;
    const int tid = threadIdx.x;
    const int tr = tid >> 4, tc = tid & 15;
    const int l_r = tid >> 3, l_k4 = (tid & 7) * 4;
    float4 ra0, rb0, rb1;
    float acc[2][4] = {};
    {
        const int k0 = kbase;
        ra0 = *(const float4*)(Amat + (size_t)(b0 + l_r)*1024 + k0 + l_k4);
        rb0 = *(const float4*)(W + (size_t)(j0 + l_r)*1024 + k0 + l_k4);
        rb1 = *(const float4*)(W + (size_t)(j0 + l_r + 32)*1024 + k0 + l_k4);
        As[0][l_k4+0][l_r] = ra0.x; As[0][l_k4+1][l_r] = ra0.y;
        As[0][l_k4+2][l_r] = ra0.z; As[0][l_k4+3][l_r] = ra0.w;
        Bs[0][l_k4+0][l_r] = rb0.x; Bs[0][l_k4+1][l_r] = rb0.y;
        Bs[0][l_k4+2][l_r] = rb0.z; Bs[0][l_k4+3][l_r] = rb0.w;
        Bs[0][l_k4+0][l_r+32] = rb1.x; Bs[0][l_k4+1][l_r+32] = rb1.y;
        Bs[0][l_k4+2][l_r+32] = rb1.z; Bs[0][l_k4+3][l_r+32] = rb1.w;
    }
    __syncthreads();
    for (int s = 0; s < 4; ++s) {
        if (s < 3) {
            const int k0 = kbase + (s+1)*32;
            ra0 = *(const float4*)(Amat + (size_t)(b0 + l_r)*1024 + k0 + l_k4);
            rb0 = *(const float4*)(W + (size_t)(j0 + l_r)*1024 + k0 + l_k4);
            rb1 = *(const float4*)(W + (size_t)(j0 + l_r + 32)*1024 + k0 + l_k4);
        }
        const int bf = s & 1;
        #pragma unroll
        for (int kk = 0; kk < 32; ++kk) {
            float a0 = As[bf][kk][tr*2], a1 = As[bf][kk][tr*2+1];
            float4 bv = *(const float4*)&Bs[bf][kk][tc*4];
            acc[0][0] += a0*bv.x; acc[0][1] += a0*bv.y; acc[0][2] += a0*bv.z; acc[0][3] += a0*bv.w;
            acc[1][0] += a1*bv.x; acc[1][1] += a1*bv.y; acc[1][2] += a1*bv.z; acc[1][3] += a1*bv.w;
        }
        if (s < 3) {
            const int nb = bf ^ 1;
            As[nb][l_k4+0][l_r] = ra0.x; As[nb][l_k4+1][l_r] = ra0.y;
            As[nb][l_k4+2][l_r] = ra0.z; As[nb][l_k4+3][l_r] = ra0.w;
            Bs[nb][l_k4+0][l_r] = rb0.x; Bs[nb][l_k4+1][l_r] = rb0.y;
            Bs[nb][l_k4+2][l_r] = rb0.z; Bs[nb][l_k4+3][l_r] = rb0.w;
            Bs[nb][l_k4+0][l_r+32] = rb1.x; Bs[nb][l_k4+1][l_r+32] = rb1.y;
            Bs[nb][l_k4+2][l_r+32] = rb1.z; Bs[nb][l_k4+3][l_r+32] = rb1.w;
        }
        __syncthreads();
    }
    #pragma unroll
    for (int r = 0; r < 2; ++r) {
        float4 o = make_float4(acc[r][0], acc[r][1], acc[r][2], acc[r][3]);
        *(float4*)(C + (size_t)(b0 + tr*2 + r)*256 + j0 + tc*4) = o;
    }
}

// K10: final LN over rows of 256; input = sum of 8 K-partials + bias.
__global__ __launch_bounds__(256) void ln_out_kernel(
        const float* __restrict__ P, const float* __restrict__ bias,
        const float* __restrict__ g, const float* __restrict__ be,
        float* __restrict__ Y) {
    int b = blockIdx.x, tid = threadIdx.x;
    __shared__ float2 red[4];
    float v0 = bias[tid];
    #pragma unroll
    for (int z = 0; z < 8; ++z) v0 += P[(size_t)z*131072 + (size_t)b*256 + tid];
    float2 v = make_float2(v0, v0*v0);
    int lane = tid & 63, wave = tid >> 6;
    for (int off = 32; off; off >>= 1) { v.x += __shfl_down(v.x, off); v.y += __shfl_down(v.y, off); }
    if (lane == 0) red[wave] = v;
    __syncthreads();
    float s = red[0].x + red[1].x + red[2].x + red[3].x;
    float s2 = red[0].y + red[1].y + red[2].y + red[3].y;
    float mu  = s  * (1.f/256.f);
    float var = s2 * (1.f/256.f) - mu*mu;
    Y[(size_t)b*256 + tid] = (v0 - mu) * rsqrtf(var + EPS) * g[tid] + be[tid];
}

// ===========================================================================
extern "C" void kernel_launch(void* const* d_in, const int* in_sizes, int n_in,
                              void* d_out, int out_size, void* d_ws, size_t ws_size,
                              hipStream_t stream) {
    const float* x    = (const float*)d_in[0];
    const float* qWe0 = (const float*)d_in[1];
    const float* qbe0 = (const float*)d_in[2];
    const float* qgi0 = (const float*)d_in[3];
    const float* qbi0 = (const float*)d_in[4];
    const float* rot0 = (const float*)d_in[5];
    const float* ent0 = (const float*)d_in[6];
    const float* qWd0 = (const float*)d_in[7];
    const float* qbd0 = (const float*)d_in[8];
    const float* qgo0 = (const float*)d_in[9];
    const float* qbo0 = (const float*)d_in[10];
    const float* qWe1 = (const float*)d_in[11];
    const float* qbe1 = (const float*)d_in[12];
    const float* qgi1 = (const float*)d_in[13];
    const float* qbi1 = (const float*)d_in[14];
    const float* rot1 = (const float*)d_in[15];
    const float* ent1 = (const float*)d_in[16];
    const float* qWd1 = (const float*)d_in[17];
    const float* qbd1 = (const float*)d_in[18];
    const float* qgo1 = (const float*)d_in[19];
    const float* qbo1 = (const float*)d_in[20];
    const float* W2   = (const float*)d_in[21];
    const float* b2   = (const float*)d_in[22];
    const float* ln2g = (const float*)d_in[23];
    const float* ln2b = (const float*)d_in[24];
    const float* Wo   = (const float*)d_in[25];
    const float* bo   = (const float*)d_in[26];
    const float* lnog = (const float*)d_in[27];
    const float* lnob = (const float*)d_in[28];
    float* out = (float*)d_out;
    float* ws  = (float*)d_ws;

    // workspace layout (float offsets)
    float2* Uc   = (float2*)ws;              // 288 float2
    float2* Cc   = Uc + 288;                 // 66 float2
    float* Yraw0 = ws + 1024;
    float* m0    = ws + 7680;
    float* Yraw1 = ws + 14336;
    float* m1    = ws + 20992;
    float* h1T   = ws + 65536;               // 262144
    float* h2T   = ws + 589824;              // 262144
    float* t3p   = ws + 851968;              // 4 x 524288
    float* t3n   = ws + 2949120;             // 524288
    float* t4p   = ws + 3473408;             // 8 x 131072

    // K1: encode layer-0 + consts
    hipLaunchKernelGGL(encode0_consts_kernel, dim3(129), dim3(256), 0, stream,
                       x, qWe0, qbe0, Yraw0, rot0, ent0, rot1, ent1, Uc, Cc);
    // K2: qsim layer-0 (fused BN/tanh) + zero Yraw1
    hipLaunchKernelGGL(qsim8_kernel, dim3(512), dim3(512), 0, stream,
                       Yraw0, qgi0, qbi0, Uc, Cc, 0, m0, Yraw1);
    // K3: decode layer-0 -> h1T
    hipLaunchKernelGGL(decode_kernel, dim3(512), dim3(512), 0, stream,
                       m0, qWd0, qbd0, qgo0, qbo0, h1T);
    // K4: encode layer-1 from k-major h1T
    hipLaunchKernelGGL(encode1_kernel, dim3(128), dim3(256), 0, stream,
                       h1T, qWe1, qbe1, Yraw1);
    // K5: qsim layer-1
    hipLaunchKernelGGL(qsim8_kernel, dim3(512), dim3(512), 0, stream,
                       Yraw1, qgi1, qbi1, Uc, Cc, 1, m1, (float*)nullptr);
    // K6: decode layer-1 -> h2T
    hipLaunchKernelGGL(decode_kernel, dim3(512), dim3(512), 0, stream,
                       m1, qWd1, qbd1, qgo1, qbo1, h2T);
    // K7: gemm1 split-K4
    hipLaunchKernelGGL(gemm1_kernel, dim3(8, 16, 4), dim3(256), 0, stream,
                       h2T, W2, t3p);
    // K8: ln+relu (4 partials)
    hipLaunchKernelGGL(ln_relu_kernel, dim3(512), dim3(256), 0, stream,
                       t3p, b2, ln2g, ln2b, t3n);
    // K9: gemm2 split-K8
    hipLaunchKernelGGL(gemm2_kernel, dim3(16, 4, 8), dim3(256), 0, stream,
                       t3n, Wo, t4p);
    // K10: final LN (8 partials)
    hipLaunchKernelGGL(ln_out_kernel, dim3(512), dim3(256), 0, stream,
                       t4p, bo, lnog, lnob, out);
}

// Round 8
// 230.583 us; speedup vs baseline: 1.0220x; 1.0220x over previous
//
#include <hip/hip_runtime.h>
#include <math.h>

#define EPS   1e-5f
#define NQ    12
#define DEPTH 3
#define BATCH 512
#define DIM   4096   // 2^NQ

__device__ inline float2 cmul(float2 a, float2 b) {
    return make_float2(a.x*b.x - a.y*b.y, a.x*b.y + a.y*b.x);
}
__device__ inline float2 cmac2(float2 ua, float2 s, float2 ub, float2 p) {
    return make_float2(ua.x*s.x - ua.y*s.y + ub.x*p.x - ub.y*p.y,
                       ua.x*s.y + ua.y*s.x + ub.x*p.y + ub.y*p.x);
}

// ===========================================================================
// qsim: 8 amps/thread, 512 threads/sample, 4 NON-overlapping 3-qubit windows.
// Window layout (HB = bit position of k's 3 bits in the amp index):
//   amp = (t>>HB)<<(HB+3) | k<<HB | (t & ((1<<HB)-1))
//   W1: HB=9  k = q{0,1,2}   (k b2=q0,b1=q1,b0=q2); t b_j = amp b_j = q(11-j)
//   W2: HB=6  k = q{3,4,5};  ctrl q2 = t bit 6
//   W3: HB=3  k = q{6,7,8};  ctrl q5 = t bit 3
//   W4: HB=0  k = q{9,10,11}; ctrl q8 = t bit 0
// Boundary CRYs (2,3),(5,6),(8,9): target in k, control = t-bit coefficient
// select -> NO cross-thread communication. 11 remaps total (= 16-amp count).
// Gate order is exact: disjoint-qubit gates commute; CRY chain preserved.
// ===========================================================================
__device__ inline int swz(int a) { return a ^ ((a >> 4) & 15); }

template<int HB> __device__ inline int ampl8(int t, int k) {
    return ((t >> HB) << (HB+3)) | (k << HB) | (t & ((1<<HB)-1));
}

template<int FHB, int THB>
__device__ inline void remap8(float2* amp, float2* lds2, int t) {
    #pragma unroll
    for (int k = 0; k < 8; ++k) lds2[swz(ampl8<FHB>(t, k))] = amp[k];
    __syncthreads();
    #pragma unroll
    for (int k = 0; k < 8; ++k) amp[k] = lds2[swz(ampl8<THB>(t, k))];
    __syncthreads();
}

template<int BP>
__device__ inline void one_q8(float2* amp, float2 u00, float2 u01, float2 u10, float2 u11) {
    #pragma unroll
    for (int g = 0; g < 4; ++g) {
        const int j0 = ((g >> BP) << (BP+1)) | (g & ((1<<BP)-1));
        const int j1 = j0 | (1 << BP);
        float2 a0 = amp[j0], a1 = amp[j1];
        amp[j0] = cmac2(u00, a0, u01, a1);
        amp[j1] = cmac2(u10, a0, u11, a1);
    }
}

// CRY with ctrl and tgt both in k bits
template<int CB, int TB>
__device__ inline void cry8(float2* amp, float co, float si) {
    #pragma unroll
    for (int m = 0; m < 8; ++m) {
        if (((m >> CB) & 1) && !((m >> TB) & 1)) {
            const int j1 = m | (1 << TB);
            float2 a0 = amp[m], a1 = amp[j1];
            amp[m]  = make_float2(co*a0.x - si*a1.x, co*a0.y - si*a1.y);
            amp[j1] = make_float2(si*a0.x + co*a1.x, si*a0.y + co*a1.y);
        }
    }
}

// CRY with ctrl = thread-bit (uniform per thread): coefficient select, tgt in k
template<int TB>
__device__ inline void crysel8(float2* amp, int ctrl, float co, float si) {
    float co2 = ctrl ? co : 1.f;
    float s2  = ctrl ? si : 0.f;
    #pragma unroll
    for (int m = 0; m < 8; ++m) {
        if (!((m >> TB) & 1)) {
            const int j1 = m | (1 << TB);
            float2 a0 = amp[m], a1 = amp[j1];
            amp[m]  = make_float2(co2*a0.x - s2*a1.x, co2*a0.y - s2*a1.y);
            amp[j1] = make_float2(s2*a0.x + co2*a1.x, s2*a0.y + co2*a1.y);
        }
    }
}

__device__ void consts_body(int t,
        const float* rot0, const float* ent0, const float* rot1, const float* ent1,
        float2* Uc, float2* Cc) {
    if (t < 72) {
        int layer = t / 36, rem = t % 36, d = rem / 12, q = rem % 12;
        const float* rot = layer ? rot1 : rot0;
        float hx = 0.5f * rot[(d*NQ + q)*3 + 0];
        float hy = 0.5f * rot[(d*NQ + q)*3 + 1];
        float hz = 0.5f * rot[(d*NQ + q)*3 + 2];
        float cx = cosf(hx), sx = sinf(hx);
        float cy = cosf(hy), sy = sinf(hy);
        float2 m00 = make_float2( cy*cx,  sy*sx);
        float2 m01 = make_float2(-sy*cx, -cy*sx);
        float2 m10 = make_float2( sy*cx, -cy*sx);
        float2 m11 = make_float2( cy*cx, -sy*sx);
        float2 ez  = make_float2(cosf(hz), -sinf(hz));
        float2 ezc = make_float2(ez.x, -ez.y);
        float2* U = Uc + t*4;
        U[0] = cmul(ez,  m00);
        U[1] = cmul(ez,  m01);
        U[2] = cmul(ezc, m10);
        U[3] = cmul(ezc, m11);
    } else if (t < 72 + 66) {
        int idx = t - 72, layer = idx / 33, rem = idx % 33;
        const float* ent = layer ? ent1 : ent0;
        float th = 0.5f * ent[rem];
        Cc[idx] = make_float2(cosf(th), sinf(th));
    }
}

// ===========================================================================
// K1: encode layer-0 (blocks 0..127, 4 rows each) + consts (block 128)
// ===========================================================================
__global__ __launch_bounds__(256) void encode0_consts_kernel(
        const float* __restrict__ X, const float* __restrict__ We,
        const float* __restrict__ be, float* __restrict__ Yraw,
        const float* __restrict__ rot0, const float* __restrict__ ent0,
        const float* __restrict__ rot1, const float* __restrict__ ent1,
        float2* __restrict__ Uc, float2* __restrict__ Cc) {
    int tid = threadIdx.x;
    if (blockIdx.x == 128) {
        consts_body(tid, rot0, ent0, rot1, ent1, Uc, Cc);
        return;
    }
    __shared__ float w[NQ][512];
    {
        const float4* src = (const float4*)We;
        float4* dst = (float4*)&w[0][0];
        #pragma unroll
        for (int i = tid; i < NQ*128; i += 256) dst[i] = src[i];
    }
    __syncthreads();
    int wave = tid >> 6, lane = tid & 63;
    int b = blockIdx.x * 4 + wave;
    const float4* xr = (const float4*)(X + (size_t)b * 512);
    float acc[NQ] = {};
    #pragma unroll
    for (int j = 0; j < 2; ++j) {
        float4 xv = xr[lane + 64*j];
        #pragma unroll
        for (int q = 0; q < NQ; ++q) {
            float4 wv = ((const float4*)&w[q][0])[lane + 64*j];
            acc[q] += xv.x*wv.x + xv.y*wv.y + xv.z*wv.z + xv.w*wv.w;
        }
    }
    #pragma unroll
    for (int q = 0; q < NQ; ++q) {
        float v = acc[q];
        #pragma unroll
        for (int off = 32; off; off >>= 1) v += __shfl_xor(v, off);
        if (lane == q) Yraw[b*NQ + q] = v + be[q];
    }
}

// ===========================================================================
// K2/K5: qsim, 512 thr/sample, 8 amps/thread, 4-window schedule,
// fused batch-BN + tanh + normalize.
// ===========================================================================
__global__ __launch_bounds__(512, 4) void qsim4w_kernel(
        const float* __restrict__ Yraw, const float* __restrict__ gi,
        const float* __restrict__ bi, const float2* __restrict__ UcAll,
        const float2* __restrict__ CcAll, int layer,
        float* __restrict__ mout, float* __restrict__ zeroY) {
    int blk = blockIdx.x, t = threadIdx.x;
    const float2* Uc = UcAll + layer * DEPTH * NQ * 4;
    const float2* Cc = CcAll + layer * DEPTH * (NQ - 1);
    __shared__ float2 lds2[DIM];
    __shared__ float sred[192];
    if (zeroY && t < NQ) zeroY[blk*NQ + t] = 0.f;

    // batch stats: thread t owns row t (3 float4 = 12 floats)
    float sum[NQ], sq[NQ];
    {
        const float4* Y4 = (const float4*)Yraw;
        float4 va = Y4[t*3+0], vb = Y4[t*3+1], vc = Y4[t*3+2];
        float r[12] = {va.x,va.y,va.z,va.w, vb.x,vb.y,vb.z,vb.w, vc.x,vc.y,vc.z,vc.w};
        #pragma unroll
        for (int q = 0; q < NQ; ++q) { sum[q] = r[q]; sq[q] = r[q]*r[q]; }
    }
    int lane = t & 63, wave = t >> 6;
    #pragma unroll
    for (int q = 0; q < NQ; ++q) {
        #pragma unroll
        for (int off = 32; off; off >>= 1) {
            sum[q] += __shfl_xor(sum[q], off);
            sq[q]  += __shfl_xor(sq[q],  off);
        }
    }
    if (lane == 0) {
        #pragma unroll
        for (int q = 0; q < NQ; ++q) {
            sred[wave*24 + q]      = sum[q];
            sred[wave*24 + 12 + q] = sq[q];
        }
    }
    __syncthreads();
    float a[NQ]; float n2 = 0.f;
    const float* yr = Yraw + blk*NQ;
    #pragma unroll
    for (int q = 0; q < NQ; ++q) {
        float s = 0.f, s2 = 0.f;
        #pragma unroll
        for (int w8 = 0; w8 < 8; ++w8) { s += sred[w8*24 + q]; s2 += sred[w8*24 + 12 + q]; }
        float mu  = s  * (1.f/512.f);
        float var = s2 * (1.f/512.f) - mu*mu;
        float val = (yr[q] - mu) * rsqrtf(var + EPS) * gi[q] + bi[q];
        a[q] = tanhf(val);
        n2 += a[q]*a[q];
    }
    float scn = (n2 > 0.f) ? rsqrtf(n2) : 1.f;
    #pragma unroll
    for (int q = 0; q < NQ; ++q) a[q] *= scn;

    // init vectors (encode RY fused with depth-0 U)
    float2 v0[NQ], v1[NQ];
    #pragma unroll
    for (int q = 0; q < NQ; ++q) {
        float sv = fminf(fabsf(a[q]), 1.f);
        float c  = sqrtf(fmaxf(1.f - sv*sv, 0.f));
        float ss = (a[q] < 0.f) ? -sv : sv;
        const float2* U = Uc + q*4;
        v0[q] = make_float2(U[0].x*c + U[1].x*ss, U[0].y*c + U[1].y*ss);
        v1[q] = make_float2(U[2].x*c + U[3].x*ss, U[2].y*c + U[3].y*ss);
    }
    // product state in W1: t bit j = qubit 11-j (j=0..8); k b2=q0,b1=q1,b0=q2
    float2 common = make_float2(1.f, 0.f);
    #pragma unroll
    for (int j = 0; j < 9; ++j)
        common = cmul(common, ((t >> j) & 1) ? v1[11-j] : v0[11-j]);
    float2 amp[8];
    amp[0] = common;
    #pragma unroll
    for (int mb = 0; mb < 3; ++mb) {
        const int qb = 2 - mb;               // k bit mb <-> qubit 2-mb
        #pragma unroll
        for (int k = 0; k < (1<<mb); ++k) {
            amp[k | (1<<mb)] = cmul(amp[k], v1[qb]);
            amp[k]           = cmul(amp[k], v0[qb]);
        }
    }

    for (int d = 0; d < DEPTH; ++d) {
        const float2* Ud = Uc + d*NQ*4;
        const float2* Cd = Cc + d*(NQ-1);
        // ---- W1: k = q{0,1,2} ----
        if (d > 0) {
            one_q8<2>(amp, Ud[0],  Ud[1],  Ud[2],  Ud[3]);    // U0
            one_q8<1>(amp, Ud[4],  Ud[5],  Ud[6],  Ud[7]);    // U1
            one_q8<0>(amp, Ud[8],  Ud[9],  Ud[10], Ud[11]);   // U2
        }
        cry8<2,1>(amp, Cd[0].x, Cd[0].y);    // CRY 0-1
        cry8<1,0>(amp, Cd[1].x, Cd[1].y);    // CRY 1-2
        remap8<9,6>(amp, lds2, t);
        // ---- W2: k = q{3,4,5}; ctrl q2 = t bit 6 ----
        if (d > 0) {
            one_q8<2>(amp, Ud[12], Ud[13], Ud[14], Ud[15]);   // U3
            one_q8<1>(amp, Ud[16], Ud[17], Ud[18], Ud[19]);   // U4
            one_q8<0>(amp, Ud[20], Ud[21], Ud[22], Ud[23]);   // U5
        }
        crysel8<2>(amp, (t >> 6) & 1, Cd[2].x, Cd[2].y);  // CRY 2-3
        cry8<2,1>(amp, Cd[3].x, Cd[3].y);    // CRY 3-4
        cry8<1,0>(amp, Cd[4].x, Cd[4].y);    // CRY 4-5
        remap8<6,3>(amp, lds2, t);
        // ---- W3: k = q{6,7,8}; ctrl q5 = t bit 3 ----
        if (d > 0) {
            one_q8<2>(amp, Ud[24], Ud[25], Ud[26], Ud[27]);   // U6
            one_q8<1>(amp, Ud[28], Ud[29], Ud[30], Ud[31]);   // U7
            one_q8<0>(amp, Ud[32], Ud[33], Ud[34], Ud[35]);   // U8
        }
        crysel8<2>(amp, (t >> 3) & 1, Cd[5].x, Cd[5].y);  // CRY 5-6
        cry8<2,1>(amp, Cd[6].x, Cd[6].y);    // CRY 6-7
        cry8<1,0>(amp, Cd[7].x, Cd[7].y);    // CRY 7-8
        remap8<3,0>(amp, lds2, t);
        // ---- W4: k = q{9,10,11}; ctrl q8 = t bit 0 ----
        if (d > 0) {
            one_q8<2>(amp, Ud[36], Ud[37], Ud[38], Ud[39]);   // U9
            one_q8<1>(amp, Ud[40], Ud[41], Ud[42], Ud[43]);   // U10
            one_q8<0>(amp, Ud[44], Ud[45], Ud[46], Ud[47]);   // U11
        }
        crysel8<2>(amp, t & 1, Cd[8].x, Cd[8].y);         // CRY 8-9
        cry8<2,1>(amp, Cd[9].x,  Cd[9].y);   // CRY 9-10
        cry8<1,0>(amp, Cd[10].x, Cd[10].y);  // CRY 10-11
        if (d < DEPTH-1) remap8<0,9>(amp, lds2, t);
    }

    // measurement in W4: amp = t<<3|k; k b2=q9,b1=q10,b0=q11; t bit j = q(8-j)
    float msum = 0.f, p9 = 0.f, p10 = 0.f, p11 = 0.f;
    #pragma unroll
    for (int k = 0; k < 8; ++k) {
        float m = amp[k].x*amp[k].x + amp[k].y*amp[k].y;
        msum += m;
        if (k & 4) p9  += m;
        if (k & 2) p10 += m;
        if (k & 1) p11 += m;
    }
    #pragma unroll
    for (int q = 0; q < NQ; ++q) {
        float v;
        if (q < 9)        v = ((t >> (8-q)) & 1) ? msum : 0.f;
        else if (q == 9)  v = p9;
        else if (q == 10) v = p10;
        else              v = p11;
        #pragma unroll
        for (int off = 32; off; off >>= 1) v += __shfl_xor(v, off);
        if (lane == 0) sred[q*8 + wave] = v;
    }
    __syncthreads();
    if (t < NQ) {
        float r = 0.f;
        #pragma unroll
        for (int w8 = 0; w8 < 8; ++w8) r += sred[t*8 + w8];
        mout[blk*NQ + t] = r;
    }
}

// ===========================================================================
// K3/K6: decode (block = hidden unit h), BN over batch, write transposed.
// ===========================================================================
__global__ __launch_bounds__(512) void decode_kernel(
        const float* __restrict__ m, const float* __restrict__ Wd,
        const float* __restrict__ bd, const float* __restrict__ go,
        const float* __restrict__ bo, float* __restrict__ outT) {
    int h = blockIdx.x, b = threadIdx.x;
    __shared__ float sm[BATCH * 13];
    __shared__ float2 red[8];
    const float4* m4 = (const float4*)m;
    for (int f4 = b; f4 < 1536; f4 += 512) {
        float4 v = m4[f4];
        int base = f4*4; int row = base/12; int q = base - row*12;
        float* dst = sm + row*13 + q;
        dst[0]=v.x; dst[1]=v.y; dst[2]=v.z; dst[3]=v.w;
    }
    __syncthreads();
    float z = bd[h];
    #pragma unroll
    for (int q = 0; q < NQ; ++q) z += sm[b*13 + q] * Wd[h*NQ + q];
    float2 v = make_float2(z, z*z);
    int lane = b & 63, wave = b >> 6;
    for (int off = 32; off; off >>= 1) { v.x += __shfl_down(v.x, off); v.y += __shfl_down(v.y, off); }
    if (lane == 0) red[wave] = v;
    __syncthreads();
    float s = 0.f, s2 = 0.f;
    #pragma unroll
    for (int wv = 0; wv < 8; ++wv) { s += red[wv].x; s2 += red[wv].y; }
    float mu  = s  * (1.f/512.f);
    float var = s2 * (1.f/512.f) - mu*mu;
    outT[(size_t)h*BATCH + b] = (z - mu) * rsqrtf(var + EPS) * go[h] + bo[h];
}

// ===========================================================================
// K4: encode layer-1 straight from k-major h1T (128 blocks, atomic partials)
// ===========================================================================
__global__ __launch_bounds__(256) void encode1_kernel(
        const float* __restrict__ h1T, const float* __restrict__ We,
        const float* __restrict__ be, float* __restrict__ Yraw1) {
    __shared__ float w[NQ][512];
    __shared__ float red[4*64*NQ];
    int tid = threadIdx.x, blk = blockIdx.x;
    {
        const float4* src = (const float4*)We;
        float4* dst = (float4*)&w[0][0];
        #pragma unroll
        for (int i = tid; i < NQ*128; i += 256) dst[i] = src[i];
    }
    __syncthreads();
    int kc = blk >> 3, bc = blk & 7;     // kc in [0,16): 32 h each
    int bl = tid & 63, hg = tid >> 6;
    int b = bc*64 + bl;
    float acc[NQ] = {};
    #pragma unroll
    for (int i = 0; i < 8; ++i) {
        int h = kc*32 + hg*8 + i;
        float xv = h1T[(size_t)h*512 + b];
        #pragma unroll
        for (int q = 0; q < NQ; ++q) acc[q] += xv * w[q][h];
    }
    #pragma unroll
    for (int q = 0; q < NQ; ++q) red[(hg*64 + bl)*NQ + q] = acc[q];
    __syncthreads();
    for (int i = tid; i < 64*NQ; i += 256) {
        int bl2 = i / NQ, q = i - bl2*NQ;
        float v = red[bl2*NQ+q] + red[(64+bl2)*NQ+q] + red[(128+bl2)*NQ+q] + red[(192+bl2)*NQ+q];
        if (kc == 0) v += be[q];
        atomicAdd(&Yraw1[(size_t)(bc*64 + bl2)*NQ + q], v);
    }
}

// ===========================================================================
// K7: GEMM1 split-K4: BM=64 BN=64 BK=32, grid (8,16,4), dbuf LDS.
// ===========================================================================
__global__ __launch_bounds__(256) void gemm1_kernel(
        const float* __restrict__ AT, const float* __restrict__ W,
        float* __restrict__ Cpart) {     // [4][512][1024]
    __shared__ float As[2][32][64];
    __shared__ float Bs[2][32][68];
    const int b0 = blockIdx.x * 64, j0 = blockIdx.y * 64;
    const int kbase = blockIdx.z * 128;
    float* C = Cpart + (size_t)blockIdx.z * 512 * 1024;
    const int tid = threadIdx.x;
    const int tr = tid >> 4, tc = tid & 15;
    const int a_kk = tid >> 4, a_f4 = tid & 15;
    const int b_jj = tid >> 3, b_k4 = (tid & 7) * 4;
    float4 ra0, ra1, rb0, rb1;
    float acc[4][4] = {};
    {
        const int k0 = kbase;
        ra0 = *(const float4*)(AT + (size_t)(k0 + a_kk)*512 + b0 + a_f4*4);
        ra1 = *(const float4*)(AT + (size_t)(k0 + a_kk + 16)*512 + b0 + a_f4*4);
        rb0 = *(const float4*)(W + (size_t)(j0 + b_jj)*512 + k0 + b_k4);
        rb1 = *(const float4*)(W + (size_t)(j0 + b_jj + 32)*512 + k0 + b_k4);
        *(float4*)&As[0][a_kk][a_f4*4] = ra0;
        *(float4*)&As[0][a_kk+16][a_f4*4] = ra1;
        Bs[0][b_k4+0][b_jj] = rb0.x; Bs[0][b_k4+1][b_jj] = rb0.y;
        Bs[0][b_k4+2][b_jj] = rb0.z; Bs[0][b_k4+3][b_jj] = rb0.w;
        Bs[0][b_k4+0][b_jj+32] = rb1.x; Bs[0][b_k4+1][b_jj+32] = rb1.y;
        Bs[0][b_k4+2][b_jj+32] = rb1.z; Bs[0][b_k4+3][b_jj+32] = rb1.w;
    }
    __syncthreads();
    for (int s = 0; s < 4; ++s) {
        if (s < 3) {
            const int k0 = kbase + (s+1)*32;
            ra0 = *(const float4*)(AT + (size_t)(k0 + a_kk)*512 + b0 + a_f4*4);
            ra1 = *(const float4*)(AT + (size_t)(k0 + a_kk + 16)*512 + b0 + a_f4*4);
            rb0 = *(const float4*)(W + (size_t)(j0 + b_jj)*512 + k0 + b_k4);
            rb1 = *(const float4*)(W + (size_t)(j0 + b_jj + 32)*512 + k0 + b_k4);
        }
        const int bf = s & 1;
        #pragma unroll
        for (int kk = 0; kk < 32; ++kk) {
            float4 a  = *(const float4*)&As[bf][kk][tr*4];
            float4 bv = *(const float4*)&Bs[bf][kk][tc*4];
            acc[0][0] += a.x*bv.x; acc[0][1] += a.x*bv.y; acc[0][2] += a.x*bv.z; acc[0][3] += a.x*bv.w;
            acc[1][0] += a.y*bv.x; acc[1][1] += a.y*bv.y; acc[1][2] += a.y*bv.z; acc[1][3] += a.y*bv.w;
            acc[2][0] += a.z*bv.x; acc[2][1] += a.z*bv.y; acc[2][2] += a.z*bv.z; acc[2][3] += a.z*bv.w;
            acc[3][0] += a.w*bv.x; acc[3][1] += a.w*bv.y; acc[3][2] += a.w*bv.z; acc[3][3] += a.w*bv.w;
        }
        if (s < 3) {
            const int nb = bf ^ 1;
            *(float4*)&As[nb][a_kk][a_f4*4] = ra0;
            *(float4*)&As[nb][a_kk+16][a_f4*4] = ra1;
            Bs[nb][b_k4+0][b_jj] = rb0.x; Bs[nb][b_k4+1][b_jj] = rb0.y;
            Bs[nb][b_k4+2][b_jj] = rb0.z; Bs[nb][b_k4+3][b_jj] = rb0.w;
            Bs[nb][b_k4+0][b_jj+32] = rb1.x; Bs[nb][b_k4+1][b_jj+32] = rb1.y;
            Bs[nb][b_k4+2][b_jj+32] = rb1.z; Bs[nb][b_k4+3][b_jj+32] = rb1.w;
        }
        __syncthreads();
    }
    #pragma unroll
    for (int r = 0; r < 4; ++r) {
        float4 o = make_float4(acc[r][0], acc[r][1], acc[r][2], acc[r][3]);
        *(float4*)(C + (size_t)(b0 + tr*4 + r)*1024 + j0 + tc*4) = o;
    }
}

// K8: LN+ReLU over rows of 1024; input = sum of 4 K-partials + bias.
__global__ __launch_bounds__(256) void ln_relu_kernel(
        const float* __restrict__ P, const float* __restrict__ bias,
        const float* __restrict__ g, const float* __restrict__ be,
        float* __restrict__ Y) {
    int b = blockIdx.x, tid = threadIdx.x;
    __shared__ float2 red[4];
    float v[4];
    #pragma unroll
    for (int j = 0; j < 4; ++j) {
        int col = tid + j*256;
        float t = bias[col];
        #pragma unroll
        for (int z = 0; z < 4; ++z) t += P[(size_t)z*524288 + (size_t)b*1024 + col];
        v[j] = t;
    }
    float2 r = make_float2(v[0]+v[1]+v[2]+v[3],
                           v[0]*v[0]+v[1]*v[1]+v[2]*v[2]+v[3]*v[3]);
    int lane = tid & 63, wave = tid >> 6;
    for (int off = 32; off; off >>= 1) { r.x += __shfl_down(r.x, off); r.y += __shfl_down(r.y, off); }
    if (lane == 0) red[wave] = r;
    __syncthreads();
    float s = red[0].x + red[1].x + red[2].x + red[3].x;
    float s2 = red[0].y + red[1].y + red[2].y + red[3].y;
    float mu  = s  * (1.f/1024.f);
    float var = s2 * (1.f/1024.f) - mu*mu;
    float inv = rsqrtf(var + EPS);
    float* yr = Y + (size_t)b * 1024;
    #pragma unroll
    for (int j = 0; j < 4; ++j) {
        int col = tid + j*256;
        yr[col] = fmaxf((v[j]-mu)*inv*g[col] + be[col], 0.f);
    }
}

// K9: GEMM2 split-K8: BM=32 BN=64 BK=32, grid (16,4,8), dbuf LDS.
__global__ __launch_bounds__(256) void gemm2_kernel(
        const float* __restrict__ Amat, const float* __restrict__ W,
        float* __restrict__ Cpart) {     // [8][512][256]
    __shared__ __align__(16) char smem[27000];
    float (*As)[32][36] = (float(*)[32][36])smem;
    float (*Bs)[32][68] = (float(*)[32][68])(smem + 9216);
    const int b0 = blockIdx.x * 32, j0 = blockIdx.y * 64;
    const int kbase = blockIdx.z * 128;
    float* C = Cpart + (size_t)blockIdx.z * 512 * 256;
    const int tid = threadIdx.x;
    const int tr = tid >> 4, tc = tid & 15;
    const int l_r = tid >> 3, l_k4 = (tid & 7) * 4;
    float4 ra0, rb0, rb1;
    float acc[2][4] = {};
    {
        const int k0 = kbase;
        ra0 = *(const float4*)(Amat + (size_t)(b0 + l_r)*1024 + k0 + l_k4);
        rb0 = *(const float4*)(W + (size_t)(j0 + l_r)*1024 + k0 + l_k4);
        rb1 = *(const float4*)(W + (size_t)(j0 + l_r + 32)*1024 + k0 + l_k4);
        As[0][l_k4+0][l_r] = ra0.x; As[0][l_k4+1][l_r] = ra0.y;
        As[0][l_k4+2][l_r] = ra0.z; As[0][l_k4+3][l_r] = ra0.w;
        Bs[0][l_k4+0][l_r] = rb0.x; Bs[0][l_k4+1][l_r] = rb0.y;
        Bs[0][l_k4+2][l_r] = rb0.z; Bs[0][l_k4+3][l_r] = rb0.w;
        Bs[0][l_k4+0][l_r+32] = rb1.x; Bs[0][l_k4+1][l_r+32] = rb1.y;
        Bs[0][l_k4+2][l_r+32] = rb1.z; Bs[0][l_k4+3][l_r+32] = rb1.w;
    }
    __syncthreads();
    for (int s = 0; s < 4; ++s) {
        if (s < 3) {
            const int k0 = kbase + (s+1)*32;
            ra0 = *(const float4*)(Amat + (size_t)(b0 + l_r)*1024 + k0 + l_k4);
            rb0 = *(const float4*)(W + (size_t)(j0 + l_r)*1024 + k0 + l_k4);
            rb1 = *(const float4*)(W + (size_t)(j0 + l_r + 32)*1024 + k0 + l_k4);
        }
        const int bf = s & 1;
        #pragma unroll
        for (int kk = 0; kk < 32; ++kk) {
            float a0 = As[bf][kk][tr*2], a1 = As[bf][kk][tr*2+1];
            float4 bv = *(const float4*)&Bs[bf][kk][tc*4];
            acc[0][0] += a0*bv.x; acc[0][1] += a0*bv.y; acc[0][2] += a0*bv.z; acc[0][3] += a0*bv.w;
            acc[1][0] += a1*bv.x; acc[1][1] += a1*bv.y; acc[1][2] += a1*bv.z; acc[1][3] += a1*bv.w;
        }
        if (s < 3) {
            const int nb = bf ^ 1;
            As[nb][l_k4+0][l_r] = ra0.x; As[nb][l_k4+1][l_r] = ra0.y;
            As[nb][l_k4+2][l_r] = ra0.z; As[nb][l_k4+3][l_r] = ra0.w;
            Bs[nb][l_k4+0][l_r] = rb0.x; Bs[nb][l_k4+1][l_r] = rb0.y;
            Bs[nb][l_k4+2][l_r] = rb0.z; Bs[nb][l_k4+3][l_r] = rb0.w;
            Bs[nb][l_k4+0][l_r+32] = rb1.x; Bs[nb][l_k4+1][l_r+32] = rb1.y;
            Bs[nb][l_k4+2][l_r+32] = rb1.z; Bs[nb][l_k4+3][l_r+32] = rb1.w;
        }
        __syncthreads();
    }
    #pragma unroll
    for (int r = 0; r < 2; ++r) {
        float4 o = make_float4(acc[r][0], acc[r][1], acc[r][2], acc[r][3]);
        *(float4*)(C + (size_t)(b0 + tr*2 + r)*256 + j0 + tc*4) = o;
    }
}

// K10: final LN over rows of 256; input = sum of 8 K-partials + bias.
__global__ __launch_bounds__(256) void ln_out_kernel(
        const float* __restrict__ P, const float* __restrict__ bias,
        const float* __restrict__ g, const float* __restrict__ be,
        float* __restrict__ Y) {
    int b = blockIdx.x, tid = threadIdx.x;
    __shared__ float2 red[4];
    float v0 = bias[tid];
    #pragma unroll
    for (int z = 0; z < 8; ++z) v0 += P[(size_t)z*131072 + (size_t)b*256 + tid];
    float2 v = make_float2(v0, v0*v0);
    int lane = tid & 63, wave = tid >> 6;
    for (int off = 32; off; off >>= 1) { v.x += __shfl_down(v.x, off); v.y += __shfl_down(v.y, off); }
    if (lane == 0) red[wave] = v;
    __syncthreads();
    float s = red[0].x + red[1].x + red[2].x + red[3].x;
    float s2 = red[0].y + red[1].y + red[2].y + red[3].y;
    float mu  = s  * (1.f/256.f);
    float var = s2 * (1.f/256.f) - mu*mu;
    Y[(size_t)b*256 + tid] = (v0 - mu) * rsqrtf(var + EPS) * g[tid] + be[tid];
}

// ===========================================================================
extern "C" void kernel_launch(void* const* d_in, const int* in_sizes, int n_in,
                              void* d_out, int out_size, void* d_ws, size_t ws_size,
                              hipStream_t stream) {
    const float* x    = (const float*)d_in[0];
    const float* qWe0 = (const float*)d_in[1];
    const float* qbe0 = (const float*)d_in[2];
    const float* qgi0 = (const float*)d_in[3];
    const float* qbi0 = (const float*)d_in[4];
    const float* rot0 = (const float*)d_in[5];
    const float* ent0 = (const float*)d_in[6];
    const float* qWd0 = (const float*)d_in[7];
    const float* qbd0 = (const float*)d_in[8];
    const float* qgo0 = (const float*)d_in[9];
    const float* qbo0 = (const float*)d_in[10];
    const float* qWe1 = (const float*)d_in[11];
    const float* qbe1 = (const float*)d_in[12];
    const float* qgi1 = (const float*)d_in[13];
    const float* qbi1 = (const float*)d_in[14];
    const float* rot1 = (const float*)d_in[15];
    const float* ent1 = (const float*)d_in[16];
    const float* qWd1 = (const float*)d_in[17];
    const float* qbd1 = (const float*)d_in[18];
    const float* qgo1 = (const float*)d_in[19];
    const float* qbo1 = (const float*)d_in[20];
    const float* W2   = (const float*)d_in[21];
    const float* b2   = (const float*)d_in[22];
    const float* ln2g = (const float*)d_in[23];
    const float* ln2b = (const float*)d_in[24];
    const float* Wo   = (const float*)d_in[25];
    const float* bo   = (const float*)d_in[26];
    const float* lnog = (const float*)d_in[27];
    const float* lnob = (const float*)d_in[28];
    float* out = (float*)d_out;
    float* ws  = (float*)d_ws;

    // workspace layout (float offsets)
    float2* Uc   = (float2*)ws;              // 288 float2
    float2* Cc   = Uc + 288;                 // 66 float2
    float* Yraw0 = ws + 1024;
    float* m0    = ws + 7680;
    float* Yraw1 = ws + 14336;
    float* m1    = ws + 20992;
    float* h1T   = ws + 65536;               // 262144
    float* h2T   = ws + 589824;              // 262144
    float* t3p   = ws + 851968;              // 4 x 524288
    float* t3n   = ws + 2949120;             // 524288
    float* t4p   = ws + 3473408;             // 8 x 131072

    // K1: encode layer-0 + consts
    hipLaunchKernelGGL(encode0_consts_kernel, dim3(129), dim3(256), 0, stream,
                       x, qWe0, qbe0, Yraw0, rot0, ent0, rot1, ent1, Uc, Cc);
    // K2: qsim layer-0 (fused BN/tanh) + zero Yraw1
    hipLaunchKernelGGL(qsim4w_kernel, dim3(512), dim3(512), 0, stream,
                       Yraw0, qgi0, qbi0, Uc, Cc, 0, m0, Yraw1);
    // K3: decode layer-0 -> h1T
    hipLaunchKernelGGL(decode_kernel, dim3(512), dim3(512), 0, stream,
                       m0, qWd0, qbd0, qgo0, qbo0, h1T);
    // K4: encode layer-1 from k-major h1T
    hipLaunchKernelGGL(encode1_kernel, dim3(128), dim3(256), 0, stream,
                       h1T, qWe1, qbe1, Yraw1);
    // K5: qsim layer-1
    hipLaunchKernelGGL(qsim4w_kernel, dim3(512), dim3(512), 0, stream,
                       Yraw1, qgi1, qbi1, Uc, Cc, 1, m1, (float*)nullptr);
    // K6: decode layer-1 -> h2T
    hipLaunchKernelGGL(decode_kernel, dim3(512), dim3(512), 0, stream,
                       m1, qWd1, qbd1, qgo1, qbo1, h2T);
    // K7: gemm1 split-K4
    hipLaunchKernelGGL(gemm1_kernel, dim3(8, 16, 4), dim3(256), 0, stream,
                       h2T, W2, t3p);
    // K8: ln+relu (4 partials)
    hipLaunchKernelGGL(ln_relu_kernel, dim3(512), dim3(256), 0, stream,
                       t3p, b2, ln2g, ln2b, t3n);
    // K9: gemm2 split-K8
    hipLaunchKernelGGL(gemm2_kernel, dim3(16, 4, 8), dim3(256), 0, stream,
                       t3n, Wo, t4p);
    // K10: final LN (8 partials)
    hipLaunchKernelGGL(ln_out_kernel, dim3(512), dim3(256), 0, stream,
                       t4p, bo, lnog, lnob, out);
}

// Round 9
// 216.571 us; speedup vs baseline: 1.0881x; 1.0647x over previous
//
#include <hip/hip_runtime.h>
#include <math.h>

#define EPS   1e-5f
#define NQ    12
#define DEPTH 3
#define BATCH 512
#define DIM   4096   // 2^NQ

__device__ inline float2 cmul(float2 a, float2 b) {
    return make_float2(a.x*b.x - a.y*b.y, a.x*b.y + a.y*b.x);
}
__device__ inline float2 cmac2(float2 ua, float2 s, float2 ub, float2 p) {
    return make_float2(ua.x*s.x - ua.y*s.y + ub.x*p.x - ub.y*p.y,
                       ua.x*s.y + ua.y*s.x + ub.x*p.y + ub.y*p.x);
}

// ===========================================================================
// qsim: 16 amps/thread, 256 threads/sample, 3 windows of 4 qubits.
//   amp = (t>>HB)<<(HB+4) | k<<HB | (t & ((1<<HB)-1))
//   W1: HB=8  k b3..b0 = q0,q1,q2,q3 ; t bit j = amp bit j = q(11-j)
//   W2: HB=4  k b3..b0 = q4,q5,q6,q7 ; ctrl q3 = t bit 4
//   W3: HB=0  k b3..b0 = q8,q9,q10,q11 ; ctrl q7 = t bit 0
// Boundary CRYs (3,4),(7,8): tgt in k, ctrl = thread-bit coefficient select.
// 8 remaps total; each remap = ONE barrier via alternating LDS buffers.
// Gate order exact: disjoint-qubit commutation; CRY chain order preserved.
// ===========================================================================
__device__ inline int swz(int a) { return a ^ ((a >> 4) & 15); }

template<int HB> __device__ inline int ampl16(int t, int k) {
    return ((t >> HB) << (HB+4)) | (k << HB) | (t & ((1<<HB)-1));
}

// dbuf remap: write lds, ONE barrier, read lds. Caller alternates buffers.
template<int FHB, int THB>
__device__ inline void remap16(float2* amp, float2* lds, int t) {
    #pragma unroll
    for (int k = 0; k < 16; ++k) lds[swz(ampl16<FHB>(t, k))] = amp[k];
    __syncthreads();
    #pragma unroll
    for (int k = 0; k < 16; ++k) amp[k] = lds[swz(ampl16<THB>(t, k))];
}

template<int BP>
__device__ inline void one_q(float2* amp, float2 u00, float2 u01, float2 u10, float2 u11) {
    #pragma unroll
    for (int g = 0; g < 8; ++g) {
        const int j0 = ((g >> BP) << (BP+1)) | (g & ((1<<BP)-1));
        const int j1 = j0 | (1 << BP);
        float2 a0 = amp[j0], a1 = amp[j1];
        amp[j0] = cmac2(u00, a0, u01, a1);
        amp[j1] = cmac2(u10, a0, u11, a1);
    }
}

template<int CB, int TB>
__device__ inline void cry_rr(float2* amp, float co, float si) {
    #pragma unroll
    for (int m = 0; m < 16; ++m) {
        if (((m >> CB) & 1) && !((m >> TB) & 1)) {
            const int j1 = m | (1 << TB);
            float2 a0 = amp[m], a1 = amp[j1];
            amp[m]  = make_float2(co*a0.x - si*a1.x, co*a0.y - si*a1.y);
            amp[j1] = make_float2(si*a0.x + co*a1.x, si*a0.y + co*a1.y);
        }
    }
}

// CRY with ctrl = thread-bit (coefficient select), tgt in k bits
template<int TB>
__device__ inline void crysel16(float2* amp, int ctrl, float co, float si) {
    float co2 = ctrl ? co : 1.f;
    float s2  = ctrl ? si : 0.f;
    #pragma unroll
    for (int m = 0; m < 16; ++m) {
        if (!((m >> TB) & 1)) {
            const int j1 = m | (1 << TB);
            float2 a0 = amp[m], a1 = amp[j1];
            amp[m]  = make_float2(co2*a0.x - s2*a1.x, co2*a0.y - s2*a1.y);
            amp[j1] = make_float2(s2*a0.x + co2*a1.x, s2*a0.y + co2*a1.y);
        }
    }
}

__device__ void consts_body(int t,
        const float* rot0, const float* ent0, const float* rot1, const float* ent1,
        float2* Uc, float2* Cc) {
    if (t < 72) {
        int layer = t / 36, rem = t % 36, d = rem / 12, q = rem % 12;
        const float* rot = layer ? rot1 : rot0;
        float hx = 0.5f * rot[(d*NQ + q)*3 + 0];
        float hy = 0.5f * rot[(d*NQ + q)*3 + 1];
        float hz = 0.5f * rot[(d*NQ + q)*3 + 2];
        float cx = cosf(hx), sx = sinf(hx);
        float cy = cosf(hy), sy = sinf(hy);
        float2 m00 = make_float2( cy*cx,  sy*sx);
        float2 m01 = make_float2(-sy*cx, -cy*sx);
        float2 m10 = make_float2( sy*cx, -cy*sx);
        float2 m11 = make_float2( cy*cx, -sy*sx);
        float2 ez  = make_float2(cosf(hz), -sinf(hz));
        float2 ezc = make_float2(ez.x, -ez.y);
        float2* U = Uc + t*4;
        U[0] = cmul(ez,  m00);
        U[1] = cmul(ez,  m01);
        U[2] = cmul(ezc, m10);
        U[3] = cmul(ezc, m11);
    } else if (t < 72 + 66) {
        int idx = t - 72, layer = idx / 33, rem = idx % 33;
        const float* ent = layer ? ent1 : ent0;
        float th = 0.5f * ent[rem];
        Cc[idx] = make_float2(cosf(th), sinf(th));
    }
}

// ===========================================================================
// K1: encode layer-0 (blocks 0..127, 4 rows each) + consts (block 128)
// ===========================================================================
__global__ __launch_bounds__(256) void encode0_consts_kernel(
        const float* __restrict__ X, const float* __restrict__ We,
        const float* __restrict__ be, float* __restrict__ Yraw,
        const float* __restrict__ rot0, const float* __restrict__ ent0,
        const float* __restrict__ rot1, const float* __restrict__ ent1,
        float2* __restrict__ Uc, float2* __restrict__ Cc) {
    int tid = threadIdx.x;
    if (blockIdx.x == 128) {
        consts_body(tid, rot0, ent0, rot1, ent1, Uc, Cc);
        return;
    }
    __shared__ float w[NQ][512];
    {
        const float4* src = (const float4*)We;
        float4* dst = (float4*)&w[0][0];
        #pragma unroll
        for (int i = tid; i < NQ*128; i += 256) dst[i] = src[i];
    }
    __syncthreads();
    int wave = tid >> 6, lane = tid & 63;
    int b = blockIdx.x * 4 + wave;
    const float4* xr = (const float4*)(X + (size_t)b * 512);
    float acc[NQ] = {};
    #pragma unroll
    for (int j = 0; j < 2; ++j) {
        float4 xv = xr[lane + 64*j];
        #pragma unroll
        for (int q = 0; q < NQ; ++q) {
            float4 wv = ((const float4*)&w[q][0])[lane + 64*j];
            acc[q] += xv.x*wv.x + xv.y*wv.y + xv.z*wv.z + xv.w*wv.w;
        }
    }
    #pragma unroll
    for (int q = 0; q < NQ; ++q) {
        float v = acc[q];
        #pragma unroll
        for (int off = 32; off; off >>= 1) v += __shfl_xor(v, off);
        if (lane == q) Yraw[b*NQ + q] = v + be[q];
    }
}

// ===========================================================================
// K2/K5: qsim, 256 thr/sample, 16 amps/thread, 3-window schedule,
// dbuf single-barrier remaps, fused batch-BN + tanh + normalize.
// ===========================================================================
__global__ __launch_bounds__(256, 2) void qsim3w_kernel(
        const float* __restrict__ Yraw, const float* __restrict__ gi,
        const float* __restrict__ bi, const float2* __restrict__ UcAll,
        const float2* __restrict__ CcAll, int layer,
        float* __restrict__ mout, float* __restrict__ zeroY) {
    int blk = blockIdx.x, t = threadIdx.x;
    const float2* Uc = UcAll + layer * DEPTH * NQ * 4;
    const float2* Cc = CcAll + layer * DEPTH * (NQ - 1);
    __shared__ float2 lds2[2][DIM];      // double buffer: 1 barrier per remap
    __shared__ float sred[96];
    if (zeroY && t < NQ) zeroY[blk*NQ + t] = 0.f;

    // batch stats from full Yraw (thread t owns rows 2t, 2t+1)
    float sum[NQ] = {}, sq[NQ] = {};
    {
        const float4* Y4 = (const float4*)Yraw;
        #pragma unroll
        for (int j = 0; j < 6; ++j) {
            float4 v = Y4[t*6 + j];
            int q0 = (j*4) % 12;
            sum[q0+0]+=v.x; sq[q0+0]+=v.x*v.x;
            sum[q0+1]+=v.y; sq[q0+1]+=v.y*v.y;
            sum[q0+2]+=v.z; sq[q0+2]+=v.z*v.z;
            sum[q0+3]+=v.w; sq[q0+3]+=v.w*v.w;
        }
    }
    int lane = t & 63, wave = t >> 6;
    #pragma unroll
    for (int q = 0; q < NQ; ++q) {
        #pragma unroll
        for (int off = 32; off; off >>= 1) {
            sum[q] += __shfl_xor(sum[q], off);
            sq[q]  += __shfl_xor(sq[q],  off);
        }
    }
    if (lane == 0) {
        #pragma unroll
        for (int q = 0; q < NQ; ++q) {
            sred[wave*24 + q]      = sum[q];
            sred[wave*24 + 12 + q] = sq[q];
        }
    }
    __syncthreads();
    float a[NQ]; float n2 = 0.f;
    const float* yr = Yraw + blk*NQ;
    #pragma unroll
    for (int q = 0; q < NQ; ++q) {
        float s  = sred[q]    + sred[24+q] + sred[48+q] + sred[72+q];
        float s2 = sred[12+q] + sred[36+q] + sred[60+q] + sred[84+q];
        float mu  = s  * (1.f/512.f);
        float var = s2 * (1.f/512.f) - mu*mu;
        float val = (yr[q] - mu) * rsqrtf(var + EPS) * gi[q] + bi[q];
        a[q] = tanhf(val);
        n2 += a[q]*a[q];
    }
    float scn = (n2 > 0.f) ? rsqrtf(n2) : 1.f;
    #pragma unroll
    for (int q = 0; q < NQ; ++q) a[q] *= scn;

    // init vectors (encode RY fused with depth-0 U)
    float2 v0[NQ], v1[NQ];
    #pragma unroll
    for (int q = 0; q < NQ; ++q) {
        float sv = fminf(fabsf(a[q]), 1.f);
        float c  = sqrtf(fmaxf(1.f - sv*sv, 0.f));
        float ss = (a[q] < 0.f) ? -sv : sv;
        const float2* U = Uc + q*4;
        v0[q] = make_float2(U[0].x*c + U[1].x*ss, U[0].y*c + U[1].y*ss);
        v1[q] = make_float2(U[2].x*c + U[3].x*ss, U[2].y*c + U[3].y*ss);
    }
    // product state in W1: t bit j = qubit 11-j; k bit m = qubit 3-m
    float2 common = make_float2(1.f, 0.f);
    #pragma unroll
    for (int j = 0; j < 8; ++j)
        common = cmul(common, ((t >> j) & 1) ? v1[11-j] : v0[11-j]);
    float2 amp[16];
    amp[0] = common;
    #pragma unroll
    for (int mb = 0; mb < 4; ++mb) {
        const int qb = 3 - mb;
        #pragma unroll
        for (int k = 0; k < (1<<mb); ++k) {
            amp[k | (1<<mb)] = cmul(amp[k], v1[qb]);
            amp[k]           = cmul(amp[k], v0[qb]);
        }
    }

    int rb = 0;   // remap buffer toggle
    for (int d = 0; d < DEPTH; ++d) {
        const float2* Ud = Uc + d*NQ*4;
        const float2* Cd = Cc + d*(NQ-1);
        // ---- W1: k = q{0,1,2,3} (q0=b3,q1=b2,q2=b1,q3=b0) ----
        if (d > 0) {
            remap16<0,8>(amp, lds2[rb], t); rb ^= 1;   // W3 -> W1
            one_q<3>(amp, Ud[0],  Ud[1],  Ud[2],  Ud[3]);    // U0
            one_q<2>(amp, Ud[4],  Ud[5],  Ud[6],  Ud[7]);    // U1
            one_q<1>(amp, Ud[8],  Ud[9],  Ud[10], Ud[11]);   // U2
            one_q<0>(amp, Ud[12], Ud[13], Ud[14], Ud[15]);   // U3
        }
        cry_rr<3,2>(amp, Cd[0].x, Cd[0].y);    // CRY 0-1
        cry_rr<2,1>(amp, Cd[1].x, Cd[1].y);    // CRY 1-2
        cry_rr<1,0>(amp, Cd[2].x, Cd[2].y);    // CRY 2-3
        remap16<8,4>(amp, lds2[rb], t); rb ^= 1;       // W1 -> W2
        // ---- W2: k = q{4,5,6,7} (q4=b3..q7=b0); ctrl q3 = t bit 4 ----
        if (d > 0) {
            one_q<3>(amp, Ud[16], Ud[17], Ud[18], Ud[19]);   // U4
            one_q<2>(amp, Ud[20], Ud[21], Ud[22], Ud[23]);   // U5
            one_q<1>(amp, Ud[24], Ud[25], Ud[26], Ud[27]);   // U6
            one_q<0>(amp, Ud[28], Ud[29], Ud[30], Ud[31]);   // U7
        }
        crysel16<3>(amp, (t >> 4) & 1, Cd[3].x, Cd[3].y);  // CRY 3-4
        cry_rr<3,2>(amp, Cd[4].x, Cd[4].y);    // CRY 4-5
        cry_rr<2,1>(amp, Cd[5].x, Cd[5].y);    // CRY 5-6
        cry_rr<1,0>(amp, Cd[6].x, Cd[6].y);    // CRY 6-7
        remap16<4,0>(amp, lds2[rb], t); rb ^= 1;       // W2 -> W3
        // ---- W3: k = q{8,9,10,11} (q8=b3..q11=b0); ctrl q7 = t bit 0 ----
        if (d > 0) {
            one_q<3>(amp, Ud[32], Ud[33], Ud[34], Ud[35]);   // U8
            one_q<2>(amp, Ud[36], Ud[37], Ud[38], Ud[39]);   // U9
            one_q<1>(amp, Ud[40], Ud[41], Ud[42], Ud[43]);   // U10
            one_q<0>(amp, Ud[44], Ud[45], Ud[46], Ud[47]);   // U11
        }
        crysel16<3>(amp, t & 1, Cd[7].x, Cd[7].y);         // CRY 7-8
        cry_rr<3,2>(amp, Cd[8].x,  Cd[8].y);   // CRY 8-9
        cry_rr<2,1>(amp, Cd[9].x,  Cd[9].y);   // CRY 9-10
        cry_rr<1,0>(amp, Cd[10].x, Cd[10].y);  // CRY 10-11
    }

    // measurement in W3: amp = t<<4|k; k b3=q8,b2=q9,b1=q10,b0=q11;
    // t bit j = qubit 7-j
    float msum = 0.f, p8 = 0.f, p9 = 0.f, p10 = 0.f, p11 = 0.f;
    #pragma unroll
    for (int k = 0; k < 16; ++k) {
        float m = amp[k].x*amp[k].x + amp[k].y*amp[k].y;
        msum += m;
        if (k & 8) p8  += m;
        if (k & 4) p9  += m;
        if (k & 2) p10 += m;
        if (k & 1) p11 += m;
    }
    #pragma unroll
    for (int q = 0; q < NQ; ++q) {
        float v;
        if (q < 8)        v = ((t >> (7-q)) & 1) ? msum : 0.f;
        else if (q == 8)  v = p8;
        else if (q == 9)  v = p9;
        else if (q == 10) v = p10;
        else              v = p11;
        #pragma unroll
        for (int off = 32; off; off >>= 1) v += __shfl_xor(v, off);
        if (lane == 0) sred[q*4 + wave] = v;
    }
    __syncthreads();
    if (t < NQ)
        mout[blk*NQ + t] = sred[t*4] + sred[t*4+1] + sred[t*4+2] + sred[t*4+3];
}

// ===========================================================================
// K3/K6: decode (block = hidden unit h), BN over batch, write transposed.
// ===========================================================================
__global__ __launch_bounds__(512) void decode_kernel(
        const float* __restrict__ m, const float* __restrict__ Wd,
        const float* __restrict__ bd, const float* __restrict__ go,
        const float* __restrict__ bo, float* __restrict__ outT) {
    int h = blockIdx.x, b = threadIdx.x;
    __shared__ float sm[BATCH * 13];
    __shared__ float2 red[8];
    const float4* m4 = (const float4*)m;
    for (int f4 = b; f4 < 1536; f4 += 512) {
        float4 v = m4[f4];
        int base = f4*4; int row = base/12; int q = base - row*12;
        float* dst = sm + row*13 + q;
        dst[0]=v.x; dst[1]=v.y; dst[2]=v.z; dst[3]=v.w;
    }
    __syncthreads();
    float z = bd[h];
    #pragma unroll
    for (int q = 0; q < NQ; ++q) z += sm[b*13 + q] * Wd[h*NQ + q];
    float2 v = make_float2(z, z*z);
    int lane = b & 63, wave = b >> 6;
    for (int off = 32; off; off >>= 1) { v.x += __shfl_down(v.x, off); v.y += __shfl_down(v.y, off); }
    if (lane == 0) red[wave] = v;
    __syncthreads();
    float s = 0.f, s2 = 0.f;
    #pragma unroll
    for (int wv = 0; wv < 8; ++wv) { s += red[wv].x; s2 += red[wv].y; }
    float mu  = s  * (1.f/512.f);
    float var = s2 * (1.f/512.f) - mu*mu;
    outT[(size_t)h*BATCH + b] = (z - mu) * rsqrtf(var + EPS) * go[h] + bo[h];
}

// ===========================================================================
// K4: encode layer-1 straight from k-major h1T (64 blocks, atomic partials)
// ===========================================================================
__global__ __launch_bounds__(256) void encode1_kernel(
        const float* __restrict__ h1T, const float* __restrict__ We,
        const float* __restrict__ be, float* __restrict__ Yraw1) {
    __shared__ float w[NQ][512];
    __shared__ float red[4*64*NQ];
    int tid = threadIdx.x, blk = blockIdx.x;
    {
        const float4* src = (const float4*)We;
        float4* dst = (float4*)&w[0][0];
        #pragma unroll
        for (int i = tid; i < NQ*128; i += 256) dst[i] = src[i];
    }
    __syncthreads();
    int kc = blk >> 3, bc = blk & 7;
    int bl = tid & 63, hg = tid >> 6;
    int b = bc*64 + bl;
    float acc[NQ] = {};
    #pragma unroll
    for (int i = 0; i < 16; ++i) {
        int h = kc*64 + hg*16 + i;
        float xv = h1T[(size_t)h*512 + b];
        #pragma unroll
        for (int q = 0; q < NQ; ++q) acc[q] += xv * w[q][h];
    }
    #pragma unroll
    for (int q = 0; q < NQ; ++q) red[(hg*64 + bl)*NQ + q] = acc[q];
    __syncthreads();
    for (int i = tid; i < 64*NQ; i += 256) {
        int bl2 = i / NQ, q = i - bl2*NQ;
        float v = red[bl2*NQ+q] + red[(64+bl2)*NQ+q] + red[(128+bl2)*NQ+q] + red[(192+bl2)*NQ+q];
        if (kc == 0) v += be[q];
        atomicAdd(&Yraw1[(size_t)(bc*64 + bl2)*NQ + q], v);
    }
}

// ===========================================================================
// K7: GEMM1 split-K4: BM=64 BN=64 BK=32, grid (8,16,4), dbuf LDS.
// ===========================================================================
__global__ __launch_bounds__(256) void gemm1_kernel(
        const float* __restrict__ AT, const float* __restrict__ W,
        float* __restrict__ Cpart) {     // [4][512][1024]
    __shared__ float As[2][32][64];
    __shared__ float Bs[2][32][68];
    const int b0 = blockIdx.x * 64, j0 = blockIdx.y * 64;
    const int kbase = blockIdx.z * 128;
    float* C = Cpart + (size_t)blockIdx.z * 512 * 1024;
    const int tid = threadIdx.x;
    const int tr = tid >> 4, tc = tid & 15;
    const int a_kk = tid >> 4, a_f4 = tid & 15;
    const int b_jj = tid >> 3, b_k4 = (tid & 7) * 4;
    float4 ra0, ra1, rb0, rb1;
    float acc[4][4] = {};
    {
        const int k0 = kbase;
        ra0 = *(const float4*)(AT + (size_t)(k0 + a_kk)*512 + b0 + a_f4*4);
        ra1 = *(const float4*)(AT + (size_t)(k0 + a_kk + 16)*512 + b0 + a_f4*4);
        rb0 = *(const float4*)(W + (size_t)(j0 + b_jj)*512 + k0 + b_k4);
        rb1 = *(const float4*)(W + (size_t)(j0 + b_jj + 32)*512 + k0 + b_k4);
        *(float4*)&As[0][a_kk][a_f4*4] = ra0;
        *(float4*)&As[0][a_kk+16][a_f4*4] = ra1;
        Bs[0][b_k4+0][b_jj] = rb0.x; Bs[0][b_k4+1][b_jj] = rb0.y;
        Bs[0][b_k4+2][b_jj] = rb0.z; Bs[0][b_k4+3][b_jj] = rb0.w;
        Bs[0][b_k4+0][b_jj+32] = rb1.x; Bs[0][b_k4+1][b_jj+32] = rb1.y;
        Bs[0][b_k4+2][b_jj+32] = rb1.z; Bs[0][b_k4+3][b_jj+32] = rb1.w;
    }
    __syncthreads();
    for (int s = 0; s < 4; ++s) {
        if (s < 3) {
            const int k0 = kbase + (s+1)*32;
            ra0 = *(const float4*)(AT + (size_t)(k0 + a_kk)*512 + b0 + a_f4*4);
            ra1 = *(const float4*)(AT + (size_t)(k0 + a_kk + 16)*512 + b0 + a_f4*4);
            rb0 = *(const float4*)(W + (size_t)(j0 + b_jj)*512 + k0 + b_k4);
            rb1 = *(const float4*)(W + (size_t)(j0 + b_jj + 32)*512 + k0 + b_k4);
        }
        const int bf = s & 1;
        #pragma unroll
        for (int kk = 0; kk < 32; ++kk) {
            float4 a  = *(const float4*)&As[bf][kk][tr*4];
            float4 bv = *(const float4*)&Bs[bf][kk][tc*4];
            acc[0][0] += a.x*bv.x; acc[0][1] += a.x*bv.y; acc[0][2] += a.x*bv.z; acc[0][3] += a.x*bv.w;
            acc[1][0] += a.y*bv.x; acc[1][1] += a.y*bv.y; acc[1][2] += a.y*bv.z; acc[1][3] += a.y*bv.w;
            acc[2][0] += a.z*bv.x; acc[2][1] += a.z*bv.y; acc[2][2] += a.z*bv.z; acc[2][3] += a.z*bv.w;
            acc[3][0] += a.w*bv.x; acc[3][1] += a.w*bv.y; acc[3][2] += a.w*bv.z; acc[3][3] += a.w*bv.w;
        }
        if (s < 3) {
            const int nb = bf ^ 1;
            *(float4*)&As[nb][a_kk][a_f4*4] = ra0;
            *(float4*)&As[nb][a_kk+16][a_f4*4] = ra1;
            Bs[nb][b_k4+0][b_jj] = rb0.x; Bs[nb][b_k4+1][b_jj] = rb0.y;
            Bs[nb][b_k4+2][b_jj] = rb0.z; Bs[nb][b_k4+3][b_jj] = rb0.w;
            Bs[nb][b_k4+0][b_jj+32] = rb1.x; Bs[nb][b_k4+1][b_jj+32] = rb1.y;
            Bs[nb][b_k4+2][b_jj+32] = rb1.z; Bs[nb][b_k4+3][b_jj+32] = rb1.w;
        }
        __syncthreads();
    }
    #pragma unroll
    for (int r = 0; r < 4; ++r) {
        float4 o = make_float4(acc[r][0], acc[r][1], acc[r][2], acc[r][3]);
        *(float4*)(C + (size_t)(b0 + tr*4 + r)*1024 + j0 + tc*4) = o;
    }
}

// K8: LN+ReLU over rows of 1024; input = sum of 4 K-partials + bias.
__global__ __launch_bounds__(256) void ln_relu_kernel(
        const float* __restrict__ P, const float* __restrict__ bias,
        const float* __restrict__ g, const float* __restrict__ be,
        float* __restrict__ Y) {
    int b = blockIdx.x, tid = threadIdx.x;
    __shared__ float2 red[4];
    float v[4];
    #pragma unroll
    for (int j = 0; j < 4; ++j) {
        int col = tid + j*256;
        float t = bias[col];
        #pragma unroll
        for (int z = 0; z < 4; ++z) t += P[(size_t)z*524288 + (size_t)b*1024 + col];
        v[j] = t;
    }
    float2 r = make_float2(v[0]+v[1]+v[2]+v[3],
                           v[0]*v[0]+v[1]*v[1]+v[2]*v[2]+v[3]*v[3]);
    int lane = tid & 63, wave = tid >> 6;
    for (int off = 32; off; off >>= 1) { r.x += __shfl_down(r.x, off); r.y += __shfl_down(r.y, off); }
    if (lane == 0) red[wave] = r;
    __syncthreads();
    float s = red[0].x + red[1].x + red[2].x + red[3].x;
    float s2 = red[0].y + red[1].y + red[2].y + red[3].y;
    float mu  = s  * (1.f/1024.f);
    float var = s2 * (1.f/1024.f) - mu*mu;
    float inv = rsqrtf(var + EPS);
    float* yr = Y + (size_t)b * 1024;
    #pragma unroll
    for (int j = 0; j < 4; ++j) {
        int col = tid + j*256;
        yr[col] = fmaxf((v[j]-mu)*inv*g[col] + be[col], 0.f);
    }
}

// K9: GEMM2 split-K8: BM=32 BN=64 BK=32, grid (16,4,8), dbuf LDS.
__global__ __launch_bounds__(256) void gemm2_kernel(
        const float* __restrict__ Amat, const float* __restrict__ W,
        float* __restrict__ Cpart) {     // [8][512][256]
    __shared__ __align__(16) char smem[27000];
    float (*As)[32][36] = (float(*)[32][36])smem;
    float (*Bs)[32][68] = (float(*)[32][68])(smem + 9216);
    const int b0 = blockIdx.x * 32, j0 = blockIdx.y * 64;
    const int kbase = blockIdx.z * 128;
    float* C = Cpart + (size_t)blockIdx.z * 512 * 256;
    const int tid = threadIdx.x;
    const int tr = tid >> 4, tc = tid & 15;
    const int l_r = tid >> 3, l_k4 = (tid & 7) * 4;
    float4 ra0, rb0, rb1;
    float acc[2][4] = {};
    {
        const int k0 = kbase;
        ra0 = *(const float4*)(Amat + (size_t)(b0 + l_r)*1024 + k0 + l_k4);
        rb0 = *(const float4*)(W + (size_t)(j0 + l_r)*1024 + k0 + l_k4);
        rb1 = *(const float4*)(W + (size_t)(j0 + l_r + 32)*1024 + k0 + l_k4);
        As[0][l_k4+0][l_r] = ra0.x; As[0][l_k4+1][l_r] = ra0.y;
        As[0][l_k4+2][l_r] = ra0.z; As[0][l_k4+3][l_r] = ra0.w;
        Bs[0][l_k4+0][l_r] = rb0.x; Bs[0][l_k4+1][l_r] = rb0.y;
        Bs[0][l_k4+2][l_r] = rb0.z; Bs[0][l_k4+3][l_r] = rb0.w;
        Bs[0][l_k4+0][l_r+32] = rb1.x; Bs[0][l_k4+1][l_r+32] = rb1.y;
        Bs[0][l_k4+2][l_r+32] = rb1.z; Bs[0][l_k4+3][l_r+32] = rb1.w;
    }
    __syncthreads();
    for (int s = 0; s < 4; ++s) {
        if (s < 3) {
            const int k0 = kbase + (s+1)*32;
            ra0 = *(const float4*)(Amat + (size_t)(b0 + l_r)*1024 + k0 + l_k4);
            rb0 = *(const float4*)(W + (size_t)(j0 + l_r)*1024 + k0 + l_k4);
            rb1 = *(const float4*)(W + (size_t)(j0 + l_r + 32)*1024 + k0 + l_k4);
        }
        const int bf = s & 1;
        #pragma unroll
        for (int kk = 0; kk < 32; ++kk) {
            float a0 = As[bf][kk][tr*2], a1 = As[bf][kk][tr*2+1];
            float4 bv = *(const float4*)&Bs[bf][kk][tc*4];
            acc[0][0] += a0*bv.x; acc[0][1] += a0*bv.y; acc[0][2] += a0*bv.z; acc[0][3] += a0*bv.w;
            acc[1][0] += a1*bv.x; acc[1][1] += a1*bv.y; acc[1][2] += a1*bv.z; acc[1][3] += a1*bv.w;
        }
        if (s < 3) {
            const int nb = bf ^ 1;
            As[nb][l_k4+0][l_r] = ra0.x; As[nb][l_k4+1][l_r] = ra0.y;
            As[nb][l_k4+2][l_r] = ra0.z; As[nb][l_k4+3][l_r] = ra0.w;
            Bs[nb][l_k4+0][l_r] = rb0.x; Bs[nb][l_k4+1][l_r] = rb0.y;
            Bs[nb][l_k4+2][l_r] = rb0.z; Bs[nb][l_k4+3][l_r] = rb0.w;
            Bs[nb][l_k4+0][l_r+32] = rb1.x; Bs[nb][l_k4+1][l_r+32] = rb1.y;
            Bs[nb][l_k4+2][l_r+32] = rb1.z; Bs[nb][l_k4+3][l_r+32] = rb1.w;
        }
        __syncthreads();
    }
    #pragma unroll
    for (int r = 0; r < 2; ++r) {
        float4 o = make_float4(acc[r][0], acc[r][1], acc[r][2], acc[r][3]);
        *(float4*)(C + (size_t)(b0 + tr*2 + r)*256 + j0 + tc*4) = o;
    }
}

// K10: final LN over rows of 256; input = sum of 8 K-partials + bias.
__global__ __launch_bounds__(256) void ln_out_kernel(
        const float* __restrict__ P, const float* __restrict__ bias,
        const float* __restrict__ g, const float* __restrict__ be,
        float* __restrict__ Y) {
    int b = blockIdx.x, tid = threadIdx.x;
    __shared__ float2 red[4];
    float v0 = bias[tid];
    #pragma unroll
    for (int z = 0; z < 8; ++z) v0 += P[(size_t)z*131072 + (size_t)b*256 + tid];
    float2 v = make_float2(v0, v0*v0);
    int lane = tid & 63, wave = tid >> 6;
    for (int off = 32; off; off >>= 1) { v.x += __shfl_down(v.x, off); v.y += __shfl_down(v.y, off); }
    if (lane == 0) red[wave] = v;
    __syncthreads();
    float s = red[0].x + red[1].x + red[2].x + red[3].x;
    float s2 = red[0].y + red[1].y + red[2].y + red[3].y;
    float mu  = s  * (1.f/256.f);
    float var = s2 * (1.f/256.f) - mu*mu;
    Y[(size_t)b*256 + tid] = (v0 - mu) * rsqrtf(var + EPS) * g[tid] + be[tid];
}

// ===========================================================================
extern "C" void kernel_launch(void* const* d_in, const int* in_sizes, int n_in,
                              void* d_out, int out_size, void* d_ws, size_t ws_size,
                              hipStream_t stream) {
    const float* x    = (const float*)d_in[0];
    const float* qWe0 = (const float*)d_in[1];
    const float* qbe0 = (const float*)d_in[2];
    const float* qgi0 = (const float*)d_in[3];
    const float* qbi0 = (const float*)d_in[4];
    const float* rot0 = (const float*)d_in[5];
    const float* ent0 = (const float*)d_in[6];
    const float* qWd0 = (const float*)d_in[7];
    const float* qbd0 = (const float*)d_in[8];
    const float* qgo0 = (const float*)d_in[9];
    const float* qbo0 = (const float*)d_in[10];
    const float* qWe1 = (const float*)d_in[11];
    const float* qbe1 = (const float*)d_in[12];
    const float* qgi1 = (const float*)d_in[13];
    const float* qbi1 = (const float*)d_in[14];
    const float* rot1 = (const float*)d_in[15];
    const float* ent1 = (const float*)d_in[16];
    const float* qWd1 = (const float*)d_in[17];
    const float* qbd1 = (const float*)d_in[18];
    const float* qgo1 = (const float*)d_in[19];
    const float* qbo1 = (const float*)d_in[20];
    const float* W2   = (const float*)d_in[21];
    const float* b2   = (const float*)d_in[22];
    const float* ln2g = (const float*)d_in[23];
    const float* ln2b = (const float*)d_in[24];
    const float* Wo   = (const float*)d_in[25];
    const float* bo   = (const float*)d_in[26];
    const float* lnog = (const float*)d_in[27];
    const float* lnob = (const float*)d_in[28];
    float* out = (float*)d_out;
    float* ws  = (float*)d_ws;

    // workspace layout (float offsets)
    float2* Uc   = (float2*)ws;              // 288 float2
    float2* Cc   = Uc + 288;                 // 66 float2
    float* Yraw0 = ws + 1024;
    float* m0    = ws + 7680;
    float* Yraw1 = ws + 14336;
    float* m1    = ws + 20992;
    float* h1T   = ws + 65536;               // 262144
    float* h2T   = ws + 589824;              // 262144
    float* t3p   = ws + 851968;              // 4 x 524288
    float* t3n   = ws + 2949120;             // 524288
    float* t4p   = ws + 3473408;             // 8 x 131072

    // K1: encode layer-0 + consts
    hipLaunchKernelGGL(encode0_consts_kernel, dim3(129), dim3(256), 0, stream,
                       x, qWe0, qbe0, Yraw0, rot0, ent0, rot1, ent1, Uc, Cc);
    // K2: qsim layer-0 (fused BN/tanh) + zero Yraw1
    hipLaunchKernelGGL(qsim3w_kernel, dim3(512), dim3(256), 0, stream,
                       Yraw0, qgi0, qbi0, Uc, Cc, 0, m0, Yraw1);
    // K3: decode layer-0 -> h1T
    hipLaunchKernelGGL(decode_kernel, dim3(512), dim3(512), 0, stream,
                       m0, qWd0, qbd0, qgo0, qbo0, h1T);
    // K4: encode layer-1 from k-major h1T
    hipLaunchKernelGGL(encode1_kernel, dim3(64), dim3(256), 0, stream,
                       h1T, qWe1, qbe1, Yraw1);
    // K5: qsim layer-1
    hipLaunchKernelGGL(qsim3w_kernel, dim3(512), dim3(256), 0, stream,
                       Yraw1, qgi1, qbi1, Uc, Cc, 1, m1, (float*)nullptr);
    // K6: decode layer-1 -> h2T
    hipLaunchKernelGGL(decode_kernel, dim3(512), dim3(512), 0, stream,
                       m1, qWd1, qbd1, qgo1, qbo1, h2T);
    // K7: gemm1 split-K4
    hipLaunchKernelGGL(gemm1_kernel, dim3(8, 16, 4), dim3(256), 0, stream,
                       h2T, W2, t3p);
    // K8: ln+relu (4 partials)
    hipLaunchKernelGGL(ln_relu_kernel, dim3(512), dim3(256), 0, stream,
                       t3p, b2, ln2g, ln2b, t3n);
    // K9: gemm2 split-K8
    hipLaunchKernelGGL(gemm2_kernel, dim3(16, 4, 8), dim3(256), 0, stream,
                       t3n, Wo, t4p);
    // K10: final LN (8 partials)
    hipLaunchKernelGGL(ln_out_kernel, dim3(512), dim3(256), 0, stream,
                       t4p, bo, lnog, lnob, out);
}